// Round 11
// baseline (380.403 us; speedup 1.0000x reference)
//
#include <hip/hip_runtime.h>
#include <math.h>

#define NN 40000
#define FF 256
#define DD 64
#define LHH 200
#define BB 512
#define TDD 16
#define GE_HASH 1024
#define GE_HALF 200

typedef _Float16 h2f __attribute__((ext_vector_type(2)));

__constant__ float TFREQ[16] = {
    1.0f,            0.48696753f,    0.23713737f,    0.115478195f,
    0.056234132f,    0.027384196f,   0.013335215f,   0.0064938162f,
    0.0031622776f,   0.0015399265f,  0.00074989421f, 0.00036517414f,
    0.00017782794f,  8.6596433e-05f, 4.2169650e-05f, 2.0535251e-05f
};

__device__ __forceinline__ float fd2(unsigned a, unsigned b, float c) {
    union { unsigned u; h2f h; } ua, ub;
    ua.u = a; ub.u = b;
    return __builtin_amdgcn_fdot2(ua.h, ub.h, c, false);
}
__device__ __forceinline__ unsigned packrn(float a, float b) {
    union { h2f h; unsigned u; } x;
    x.h.x = (_Float16)a; x.h.y = (_Float16)b;
    return x.u;
}
__device__ __forceinline__ unsigned short f16u(float a) {
    union { _Float16 h; unsigned short u; } x;
    x.h = (_Float16)a;
    return x.u;
}
__device__ __forceinline__ float h16f(unsigned short u) {
    union { unsigned short u; _Float16 h; } x;
    x.u = u;
    return (float)x.h;
}
__device__ __forceinline__ float f16lo(unsigned u) {
    union { unsigned u; h2f h; } x; x.u = u; return (float)x.h.x;
}
__device__ __forceinline__ float f16hi(unsigned u) {
    union { unsigned u; h2f h; } x; x.u = u; return (float)x.h.y;
}
__device__ __forceinline__ unsigned pkrtz_u(float a, float b) {
    auto pk = __builtin_amdgcn_cvt_pkrtz(a, b);
    union { decltype(pk) h; unsigned u; } x;
    x.h = pk;
    return x.u;
}
__device__ __forceinline__ float dpp_xor1(float v) {
    return __int_as_float(
        __builtin_amdgcn_mov_dpp(__float_as_int(v), 0xB1, 0xF, 0xF, true));
}
__device__ __forceinline__ unsigned rlu(unsigned v, int l) {
    return (unsigned)__builtin_amdgcn_readlane((int)v, l);
}
__device__ __forceinline__ float sigm(float x) {
    return __builtin_amdgcn_rcpf(1.f + __expf(-x));
}
__device__ __forceinline__ float tanh_f(float x) {
    float e = __expf(2.f * x);
    return 1.f - 2.f * __builtin_amdgcn_rcpf(e + 1.f);
}
__device__ __forceinline__ int hlookupf(const unsigned* hkey, const int* hslot, unsigned id)
{
    unsigned p = (id * 2654435761u) & (GE_HASH - 1);
    while (hkey[p] != id) p = (p + 1) & (GE_HASH - 1);
    return hslot[p];
}

// ---------------------------------------------------------------------------
// K1: C[n][0:64] = A[n][:] @ W[64][KDIM]^T + bias
// ---------------------------------------------------------------------------
template<int KDIM>
__global__ void __launch_bounds__(256)
gemm_nt_kernel(const float* __restrict__ A, const float* __restrict__ W,
               const float* __restrict__ bias, float* __restrict__ C, int Nrows)
{
    __shared__ __align__(16) float a_t[128][8];
    __shared__ __align__(16) float wt[8][64];
    const int tid = threadIdx.x;
    const int tx = tid & 15;
    const int ty = tid >> 4;
    const int n0 = blockIdx.x * 128;

    float4 acc[8];
#pragma unroll
    for (int r = 0; r < 8; ++r) acc[r] = make_float4(0.f, 0.f, 0.f, 0.f);

    for (int kc = 0; kc < KDIM; kc += 8) {
        __syncthreads();
        {
            int r = tid >> 1;
            int cc = (tid & 1) * 4;
            int n = n0 + r;
            float4 v = make_float4(0.f, 0.f, 0.f, 0.f);
            if (n < Nrows) v = *(const float4*)(A + (size_t)n * KDIM + kc + cc);
            *(float4*)&a_t[r][cc] = v;
        }
        {
            int m = tid >> 2;
            int f0 = (tid & 3) * 2;
            float2 v = *(const float2*)(W + (size_t)m * KDIM + kc + f0);
            wt[f0][m] = v.x; wt[f0 + 1][m] = v.y;
        }
        __syncthreads();
        float4 w4[8];
#pragma unroll
        for (int f = 0; f < 8; ++f) w4[f] = *(float4*)&wt[f][tx * 4];
#pragma unroll
        for (int rr = 0; rr < 8; ++rr) {
            int row = ty + rr * 16;
            float4 a0 = *(float4*)&a_t[row][0];
            float4 a1 = *(float4*)&a_t[row][4];
            float av[8] = {a0.x, a0.y, a0.z, a0.w, a1.x, a1.y, a1.z, a1.w};
#pragma unroll
            for (int f = 0; f < 8; ++f) {
                acc[rr].x += av[f] * w4[f].x;
                acc[rr].y += av[f] * w4[f].y;
                acc[rr].z += av[f] * w4[f].z;
                acc[rr].w += av[f] * w4[f].w;
            }
        }
    }
    float4 bv = make_float4(0.f, 0.f, 0.f, 0.f);
    if (bias) bv = *(const float4*)(bias + tx * 4);
#pragma unroll
    for (int rr = 0; rr < 8; ++rr) {
        int n = n0 + ty + rr * 16;
        if (n < Nrows) {
            float4 o = acc[rr];
            o.x += bv.x; o.y += bv.y; o.z += bv.z; o.w += bv.w;
            *(float4*)(C + (size_t)n * DD + tx * 4) = o;
        }
    }
}

// ---------------------------------------------------------------------------
// Tn16[n][j] = f16( sum_k proj[n][k] * Wih[j][k] * ln_g[k] ); grid.y = L/Q.
// ---------------------------------------------------------------------------
__global__ void __launch_bounds__(256)
tn_gemm_kernel(const float* __restrict__ proj,
               const float* __restrict__ WihL, const float* __restrict__ WihQ,
               const float* __restrict__ ln_g,
               unsigned short* __restrict__ TnL, unsigned short* __restrict__ TnQ)
{
    const float* Wih = blockIdx.y ? WihQ : WihL;
    unsigned short* Tn = blockIdx.y ? TnQ : TnL;
    __shared__ float wgT[64][193];
    __shared__ __align__(16) float4 at4[64][16];
    const int tid = threadIdx.x;
    const int n0 = blockIdx.x * 64;
    for (int i = tid; i < 192 * 64; i += 256) {
        int j = i >> 6, k = i & 63;
        wgT[k][j] = Wih[i] * ln_g[k];
    }
    for (int i = tid; i < 1024; i += 256) {
        int r = i >> 4, kc = i & 15;
        at4[r][kc] = ((const float4*)(proj + (size_t)(n0 + r) * DD))[kc];
    }
    __syncthreads();
    const int c = tid & 63, wv = tid >> 6;
    float acc0[16], acc1[16], acc2[16];
#pragma unroll
    for (int r = 0; r < 16; ++r) { acc0[r] = 0.f; acc1[r] = 0.f; acc2[r] = 0.f; }
    for (int kc = 0; kc < 16; ++kc) {
        float w0[4], w1[4], w2[4];
#pragma unroll
        for (int q = 0; q < 4; ++q) {
            w0[q] = wgT[kc * 4 + q][c];
            w1[q] = wgT[kc * 4 + q][64 + c];
            w2[q] = wgT[kc * 4 + q][128 + c];
        }
#pragma unroll
        for (int r = 0; r < 16; ++r) {
            float4 a = at4[wv * 16 + r][kc];
            acc0[r] += a.x * w0[0] + a.y * w0[1] + a.z * w0[2] + a.w * w0[3];
            acc1[r] += a.x * w1[0] + a.y * w1[1] + a.z * w1[2] + a.w * w1[3];
            acc2[r] += a.x * w2[0] + a.y * w2[1] + a.z * w2[2] + a.w * w2[3];
        }
    }
#pragma unroll
    for (int r = 0; r < 16; ++r) {
        size_t row = (size_t)(n0 + wv * 16 + r) * 192;
        Tn[row + c]       = f16u(acc0[r]);
        Tn[row + 64 + c]  = f16u(acc1[r]);
        Tn[row + 128 + c] = f16u(acc2[r]);
    }
}

// ---------------------------------------------------------------------------
// Per-gate-row constants out[21][192] + f16-packed Whh + packed time weights.
// ---------------------------------------------------------------------------
__global__ void __launch_bounds__(192)
consts_kernel(const float* __restrict__ WihL, const float* __restrict__ bihL,
              const float* __restrict__ WhhL, float* __restrict__ outL,
              unsigned* __restrict__ whpL, unsigned* __restrict__ tpkL,
              const float* __restrict__ WihQ, const float* __restrict__ bihQ,
              const float* __restrict__ WhhQ, float* __restrict__ outQ,
              unsigned* __restrict__ whpQ, unsigned* __restrict__ tpkQ,
              unsigned* __restrict__ wtpk,
              const float* __restrict__ ln_g, const float* __restrict__ ln_b,
              const float* __restrict__ Wedge, const float* __restrict__ bedge,
              const float* __restrict__ Wtime, const float* __restrict__ btime,
              const float* __restrict__ Wstruct, const float* __restrict__ bstruct)
{
    const float* Wih = blockIdx.x ? WihQ : WihL;
    const float* bih = blockIdx.x ? bihQ : bihL;
    const float* Whh = blockIdx.x ? WhhQ : WhhL;
    float* out = blockIdx.x ? outQ : outL;
    unsigned* whp = blockIdx.x ? whpQ : whpL;
    unsigned* tpk = blockIdx.x ? tpkQ : tpkL;
    const int j = threadIdx.x;
    float te = 0.f, tw = 0.f, t1 = 0.f, tb0 = 0.f, cc = 0.f;
    float tt[16];
#pragma unroll
    for (int t = 0; t < 16; ++t) tt[t] = 0.f;
    for (int k = 0; k < DD; ++k) {
        float wv = Wih[j * DD + k];
        float wg = wv * ln_g[k];
        te  += wg * Wedge[k];
        tw  += wg * Wstruct[k];
        t1  += wg;
        tb0 += wg * (bedge[k] + btime[k] + 2.f * bstruct[k]);
        cc  += wv * ln_b[k];
#pragma unroll
        for (int t = 0; t < 16; ++t) tt[t] += wg * Wtime[k * TDD + t];
    }
    out[0 * 192 + j] = te;
    out[1 * 192 + j] = tw;
    out[2 * 192 + j] = t1;
    out[3 * 192 + j] = tb0;
    out[4 * 192 + j] = cc + bih[j];
    for (int t = 0; t < 16; ++t) out[(5 + t) * 192 + j] = tt[t];
    for (int q = 0; q < 8; ++q)
        tpk[j * 8 + q] = packrn(tt[2 * q], tt[2 * q + 1]);
    if (blockIdx.x == 0 && j < 64)
        for (int q = 0; q < 8; ++q)
            wtpk[j * 8 + q] = packrn(Wtime[j * TDD + 2 * q], Wtime[j * TDD + 2 * q + 1]);
    for (int k2 = 0; k2 < 32; ++k2)
        whp[j * 32 + k2] = packrn(Whh[j * DD + 2 * k2], Whh[j * DD + 2 * k2 + 1]);
}

// ---------------------------------------------------------------------------
// PRE: compute folded gate pre-activations g0,g1,g2 for every (seq, l).
// ---------------------------------------------------------------------------
struct PS {
    int nid;
    float tn0, tn1, tn2, pv, e0, sk, t;
};

__global__ void __launch_bounds__(64)
pre_kernel(const int* __restrict__ nidsL, const int* __restrict__ eidsL,
           const float* __restrict__ timesL, const int* __restrict__ curL,
           const int* __restrict__ nidsQ, const int* __restrict__ eidsQ,
           const float* __restrict__ timesQ, const int* __restrict__ curQ,
           const float* __restrict__ node_raw, const float* __restrict__ edge_raw,
           const float* __restrict__ proj_node,
           const unsigned short* __restrict__ TnL, const unsigned short* __restrict__ TnQ,
           const float* __restrict__ cstL, const float* __restrict__ cstQ,
           const unsigned* __restrict__ tpkL, const unsigned* __restrict__ tpkQ,
           const unsigned* __restrict__ wtpk,
           const float* __restrict__ bhhL, const float* __restrict__ bhhQ,
           const float* __restrict__ Wedge, const float* __restrict__ bedge,
           const float* __restrict__ Wtime, const float* __restrict__ btime,
           const float* __restrict__ Wstruct, const float* __restrict__ bstruct,
           unsigned* __restrict__ g01out, unsigned short* __restrict__ g2out)
{
    const int bq = blockIdx.x;
    const int blk = bq >> 2, qq = bq & 3;
    const int g = blk >> 9, s = blk & 511;
    const int d = threadIdx.x;

    const int*            nids  = g ? nidsQ : nidsL;
    const int*            eids  = g ? eidsQ : eidsL;
    const float*          times = g ? timesQ : timesL;
    const int*            curp  = g ? curQ : curL;
    const unsigned short* Tn    = g ? TnQ : TnL;
    const float*          cst   = g ? cstQ : cstL;
    const unsigned*       tpk   = g ? tpkQ : tpkL;
    const float*          bhh   = g ? bhhQ : bhhL;

    unsigned tp0[8], tp1[8], tp2[8], wtp[8];
#pragma unroll
    for (int q4 = 0; q4 < 2; ++q4) {
        uint4 a = *(const uint4*)(tpk + (size_t)(0 * 64 + d) * 8 + 4 * q4);
        tp0[4*q4] = a.x; tp0[4*q4+1] = a.y; tp0[4*q4+2] = a.z; tp0[4*q4+3] = a.w;
        uint4 b = *(const uint4*)(tpk + (size_t)(1 * 64 + d) * 8 + 4 * q4);
        tp1[4*q4] = b.x; tp1[4*q4+1] = b.y; tp1[4*q4+2] = b.z; tp1[4*q4+3] = b.w;
        uint4 c = *(const uint4*)(tpk + (size_t)(2 * 64 + d) * 8 + 4 * q4);
        tp2[4*q4] = c.x; tp2[4*q4+1] = c.y; tp2[4*q4+2] = c.z; tp2[4*q4+3] = c.w;
        uint4 e = *(const uint4*)(wtpk + (size_t)d * 8 + 4 * q4);
        wtp[4*q4] = e.x; wtp[4*q4+1] = e.y; wtp[4*q4+2] = e.z; wtp[4*q4+3] = e.w;
    }
    const float TE0 = cst[0*192 + d], TE1 = cst[0*192 + 64 + d], TE2 = cst[0*192 + 128 + d];
    const float TW0 = cst[1*192 + d], TW1 = cst[1*192 + 64 + d], TW2 = cst[1*192 + 128 + d];
    const float T10 = cst[2*192 + d], T11 = cst[2*192 + 64 + d], T12 = cst[2*192 + 128 + d];
    const float TB0 = cst[3*192 + d], TB1 = cst[3*192 + 64 + d], TB2 = cst[3*192 + 128 + d];
    const float CC0 = cst[4*192 + d] + bhh[d];
    const float CC1 = cst[4*192 + 64 + d] + bhh[64 + d];
    const float CC2 = cst[4*192 + 128 + d];
    const float we_l = Wedge[d];
    const float ws_l = Wstruct[d];
    const float b0_l = bedge[d] + btime[d] + 2.f * bstruct[d];
    const float tfl  = TFREQ[d & 15];

    const int cur = curp[s];
    const int csk = (int)node_raw[(size_t)cur * FF];
    const int* nrow = nids + s * LHH;
    const int* erow = eids + s * LHH;
    const float* trow = times + s * LHH;
    const int lbase = qq * 50;

    auto GATH = [&](PS& P, int i) {
        int l = lbase + i;
        int nid = nrow[l];
        int eid = erow[l];
        P.nid = nid;
        const unsigned short* tb = Tn + (size_t)nid * 192;
        P.tn0 = h16f(tb[d]);
        P.tn1 = h16f(tb[64 + d]);
        P.tn2 = h16f(tb[128 + d]);
        P.pv  = proj_node[(size_t)nid * DD + d];
        P.e0  = edge_raw[(size_t)eid * 4];
        P.sk  = node_raw[(size_t)nid * FF];
        P.t   = trow[l];
    };

    auto EMIT = [&](const PS& P, int i) {
        float cv = __cosf(P.t * tfl);
        float cx = dpp_xor1(cv);
        unsigned cp = pkrtz_u(cv, cx);
        unsigned s0 = rlu(cp, 0),  s1 = rlu(cp, 2),  s2 = rlu(cp, 4),  s3 = rlu(cp, 6);
        unsigned s4 = rlu(cp, 8),  s5 = rlu(cp, 10), s6 = rlu(cp, 12), s7 = rlu(cp, 14);
        float tf = fd2(wtp[7], s7, fd2(wtp[6], s6, fd2(wtp[5], s5, fd2(wtp[4], s4, 0.f))));
        tf = fd2(wtp[3], s3, fd2(wtp[2], s2, fd2(wtp[1], s1, fd2(wtp[0], s0, tf))));
        float flg = ((P.nid == cur) ? 1.f : 0.f) + (((int)P.sk == csk) ? 1.f : 0.f);
        float f = P.pv + P.e0 * we_l + flg * ws_l + b0_l + tf;
        float mu = f;
#pragma unroll
        for (int off = 32; off; off >>= 1) mu += __shfl_xor(mu, off);
        mu *= (1.f / 64.f);
        float dv = f - mu, var = dv * dv;
#pragma unroll
        for (int off = 32; off; off >>= 1) var += __shfl_xor(var, off);
        float rs = rsqrtf(var * (1.f / 64.f) + 1e-5f);
        float c0 = fd2(tp0[7], s7, fd2(tp0[6], s6, fd2(tp0[5], s5, fd2(tp0[4], s4, 0.f))));
        c0 = fd2(tp0[3], s3, fd2(tp0[2], s2, fd2(tp0[1], s1, fd2(tp0[0], s0, c0))));
        float c1 = fd2(tp1[7], s7, fd2(tp1[6], s6, fd2(tp1[5], s5, fd2(tp1[4], s4, 0.f))));
        c1 = fd2(tp1[3], s3, fd2(tp1[2], s2, fd2(tp1[1], s1, fd2(tp1[0], s0, c1))));
        float c2 = fd2(tp2[7], s7, fd2(tp2[6], s6, fd2(tp2[5], s5, fd2(tp2[4], s4, 0.f))));
        c2 = fd2(tp2[3], s3, fd2(tp2[2], s2, fd2(tp2[1], s1, fd2(tp2[0], s0, c2))));
        float g0 = (c0 + P.tn0 + P.e0 * TE0 + flg * TW0 + TB0 - mu * T10) * rs + CC0;
        float g1 = (c1 + P.tn1 + P.e0 * TE1 + flg * TW1 + TB1 - mu * T11) * rs + CC1;
        float g2 = (c2 + P.tn2 + P.e0 * TE2 + flg * TW2 + TB2 - mu * T12) * rs + CC2;
        size_t pos = ((size_t)blk * LHH + (lbase + i)) * 64 + d;
        g01out[pos] = packrn(g0, g1);
        g2out[pos] = f16u(g2);
    };

    PS Pc, Pn;
    GATH(Pc, 0);
    for (int i = 0; i < 50; ++i) {
        int inext = (i + 1 < 50) ? i + 1 : 49;
        GATH(Pn, inext);
        EMIT(Pc, i);
        Pc = Pn;
    }
}

// ---------------------------------------------------------------------------
// GRU-lite: ONE wave per sequence; only the h-recurrence.
// ---------------------------------------------------------------------------
__global__ void __launch_bounds__(64) __attribute__((amdgpu_waves_per_eu(1, 1)))
gru_lite_kernel(const unsigned* __restrict__ g01, const unsigned short* __restrict__ g2a,
                const unsigned* __restrict__ whpL, const unsigned* __restrict__ whpQ,
                const float* __restrict__ bhhL, const float* __restrict__ bhhQ,
                float* __restrict__ embL, float* __restrict__ embQ)
{
    const int blk = blockIdx.x;
    const int g = blk >> 9, s = blk & 511;
    const int d = threadIdx.x;

    const unsigned* whp = g ? whpQ : whpL;
    const float*    bhh = g ? bhhQ : bhhL;
    float*          emb = g ? embQ : embL;

    unsigned w0[32], w1[32], w2[32];
    {
        const unsigned* p0 = whp + (size_t)d * 32;
        const unsigned* p1 = whp + (size_t)(64 + d) * 32;
        const unsigned* p2 = whp + (size_t)(128 + d) * 32;
#pragma unroll
        for (int q4 = 0; q4 < 8; ++q4) {
            uint4 a = *(const uint4*)(p0 + 4 * q4);
            w0[4*q4] = a.x; w0[4*q4+1] = a.y; w0[4*q4+2] = a.z; w0[4*q4+3] = a.w;
            uint4 b = *(const uint4*)(p1 + 4 * q4);
            w1[4*q4] = b.x; w1[4*q4+1] = b.y; w1[4*q4+2] = b.z; w1[4*q4+3] = b.w;
            uint4 c = *(const uint4*)(p2 + 4 * q4);
            w2[4*q4] = c.x; w2[4*q4+1] = c.y; w2[4*q4+2] = c.z; w2[4*q4+3] = c.w;
        }
    }
#pragma unroll
    for (int i = 0; i < 32; ++i) {
        asm volatile("" : "+v"(w0[i]));
        asm volatile("" : "+v"(w1[i]));
        asm volatile("" : "+v"(w2[i]));
    }
    const float BH2 = bhh[128 + d];

    const unsigned* p01 = g01 + (size_t)blk * LHH * 64 + d;
    const unsigned short* p2 = g2a + (size_t)blk * LHH * 64 + d;

    float h = 0.f;

    auto COMPUTE = [&](unsigned pk01, unsigned pk2) {
        float g0 = f16lo(pk01), g1 = f16hi(pk01);
        float g2 = h16f((unsigned short)pk2);
        float hx = dpp_xor1(h);
        unsigned hpu = pkrtz_u(h, hx);
        float a0 = 0.f, a1 = 0.f, a2 = 0.f, e0 = 0.f, e1 = 0.f, e2 = 0.f;
#pragma unroll
        for (int q = 0; q < 32; q += 2) {
            unsigned sa = rlu(hpu, 2 * q);
            unsigned sb = rlu(hpu, 2 * q + 2);
            a0 = fd2(w0[q], sa, a0);
            a1 = fd2(w1[q], sa, a1);
            a2 = fd2(w2[q], sa, a2);
            e0 = fd2(w0[q+1], sb, e0);
            e1 = fd2(w1[q+1], sb, e1);
            e2 = fd2(w2[q+1], sb, e2);
        }
        float mv0 = a0 + e0, mv1 = a1 + e1, mv2 = a2 + e2;
        float r = sigm(g0 + mv0);
        float z = sigm(g1 + mv1);
        float n = tanh_f(g2 + r * (mv2 + BH2));
        h = (1.f - z) * n + z * h;
    };

    unsigned A01[4], A2[4], B01[4], B2[4];
#pragma unroll
    for (int i = 0; i < 4; ++i) {
        A01[i] = p01[(size_t)i * 64];
        A2[i]  = p2[(size_t)i * 64];
    }
    for (int l = 0; l < LHH; l += 8) {
#pragma unroll
        for (int i = 0; i < 4; ++i) {
            int ll = l + 4 + i;
            B01[i] = p01[(size_t)ll * 64];
            B2[i]  = p2[(size_t)ll * 64];
        }
#pragma unroll
        for (int i = 0; i < 4; ++i) COMPUTE(A01[i], A2[i]);
#pragma unroll
        for (int i = 0; i < 4; ++i) {
            int ll = l + 8 + i;
            if (ll > LHH - 1) ll = LHH - 1;
            A01[i] = p01[(size_t)ll * 64];
            A2[i]  = p2[(size_t)ll * 64];
        }
#pragma unroll
        for (int i = 0; i < 4; ++i) COMPUTE(B01[i], B2[i]);
    }
    emb[(size_t)s * DD + d] = h;
}

// ---------------------------------------------------------------------------
// K3: graph_emb — hash-dedup'd GCNConv + mean pool. Two-pass 200-slot agg
// (74 KB LDS -> 2 blocks/CU) + unroll-4 batched gathers.
// ---------------------------------------------------------------------------
__global__ void __launch_bounds__(512)
graph_emb_kernel(const int* __restrict__ retrieved, const int* __restrict__ pool_nodes,
                 const float* __restrict__ hgcn, const float* __restrict__ gcn_b,
                 float* __restrict__ glob)
{
    __shared__ float agg[GE_HALF * 64];          // 51200 B
    __shared__ unsigned hkey[GE_HASH];
    __shared__ int hslot[GE_HASH];
    __shared__ unsigned ekey[GE_HASH];
    __shared__ int slot_id[400];
    __shared__ unsigned deg[400];
    __shared__ float dis[400];
    __shared__ unsigned elist[400];
    __shared__ int ids[400];
    __shared__ int pids[8];
    __shared__ int cntU, cntE;
    __shared__ float gcnb_s[64];
    __shared__ float red[8][64];

    const int b = blockIdx.x;
    const int tid = threadIdx.x;
    const int lane = tid & 63, wid = tid >> 6;

    if (tid < 8)  pids[tid] = retrieved[b * 8 + tid];
    if (tid < 64) gcnb_s[tid] = gcn_b[tid];
    if (tid == 0) { cntU = 0; cntE = 0; }
    for (int i = tid; i < GE_HASH; i += 512) { hkey[i] = 0u; ekey[i] = 0u; }
    if (tid < 400) deg[tid] = 0u;
    __syncthreads();

    if (tid < 400) {
        int k = tid / 50, p = tid % 50;
        ids[tid] = pool_nodes[(size_t)pids[k] * 50 + p];
    }
    __syncthreads();

    if (tid < 400) {
        int idi = ids[tid];
        if (idi > 0) {
            unsigned id = (unsigned)idi;
            unsigned p = (id * 2654435761u) & (GE_HASH - 1);
            while (true) {
                unsigned old = atomicCAS(&hkey[p], 0u, id);
                if (old == 0u) {
                    int s = atomicAdd(&cntU, 1);
                    hslot[p] = s; slot_id[s] = idi;
                    break;
                }
                if (old == id) break;
                p = (p + 1) & (GE_HASH - 1);
            }
        }
    }
    __syncthreads();

    if (tid < 8 * 49) {
        int k = tid / 49, p = tid % 49;
        int u = ids[k * 50 + p], v = ids[k * 50 + p + 1];
        if (u > 0 && v > 0) {
            unsigned a = (unsigned)min(u, v), bb = (unsigned)max(u, v);
            unsigned key = a * 40000u + bb;
            unsigned p2 = (key * 2654435761u) & (GE_HASH - 1);
            while (true) {
                unsigned old = atomicCAS(&ekey[p2], 0u, key);
                if (old == 0u) {
                    int su = hlookupf(hkey, hslot, a);
                    int sv = hlookupf(hkey, hslot, bb);
                    int e = atomicAdd(&cntE, 1);
                    elist[e] = ((unsigned)su << 16) | (unsigned)sv;
                    atomicAdd(&deg[su], 1u);
                    atomicAdd(&deg[sv], 1u);
                    break;
                }
                if (old == key) break;
                p2 = (p2 + 1) & (GE_HASH - 1);
            }
        }
    }
    __syncthreads();

    const int U = cntU, EC = cntE;
    if (tid < U) dis[tid] = rsqrtf((float)deg[tid] + 1.0f);
    __syncthreads();

    float acc = 0.f;

    for (int half = 0; half < 2; ++half) {
        const int base = half * GE_HALF;
        int count = U - base;
        if (count <= 0) break;
        if (count > GE_HALF) count = GE_HALF;

        // init agg slots [base, base+count): gcn_b + dis^2 * h_self
        for (int s0 = base + wid * 4; s0 < base + count; s0 += 32) {
            float hv[4], d2[4];
#pragma unroll
            for (int j = 0; j < 4; ++j) {
                int s = s0 + j;
                int sc = (s < base + count) ? s : s0;
                hv[j] = hgcn[(size_t)slot_id[sc] * 64 + lane];
                d2[j] = dis[sc] * dis[sc];
            }
#pragma unroll
            for (int j = 0; j < 4; ++j) {
                int s = s0 + j;
                if (s < base + count)
                    agg[(s - base) * 64 + lane] = gcnb_s[lane] + d2[j] * hv[j];
            }
        }
        __syncthreads();

        // edge contributions into this slot range
        for (int e0 = wid * 4; e0 < EC; e0 += 32) {
            int su[4], sv[4];
            float hu[4], hv[4], nr[4];
#pragma unroll
            for (int j = 0; j < 4; ++j) {
                int e = e0 + j;
                if (e >= EC) e = e0;
                unsigned pk = elist[e];
                su[j] = (int)(pk >> 16);
                sv[j] = (int)(pk & 0xffffu);
                hu[j] = hgcn[(size_t)slot_id[su[j]] * 64 + lane];
                hv[j] = hgcn[(size_t)slot_id[sv[j]] * 64 + lane];
                nr[j] = dis[su[j]] * dis[sv[j]];
            }
#pragma unroll
            for (int j = 0; j < 4; ++j) {
                if (e0 + j < EC) {
                    int aa = su[j] - base, bb = sv[j] - base;
                    if (bb >= 0 && bb < GE_HALF) atomicAdd(&agg[bb * 64 + lane], nr[j] * hu[j]);
                    if (aa >= 0 && aa < GE_HALF) atomicAdd(&agg[aa * 64 + lane], nr[j] * hv[j]);
                }
            }
        }
        __syncthreads();

        // relu-sum this half
        for (int s = wid; s < count; s += 8)
            acc += fmaxf(agg[s * 64 + lane], 0.f);
        __syncthreads();
    }

    red[wid][lane] = acc;
    __syncthreads();
    if (tid < 64) {
        float tot = 0.f;
#pragma unroll
        for (int q = 0; q < 8; ++q) tot += red[q][tid];
        glob[(size_t)b * 64 + tid] = tot / (float)max(U, 1);
    }
}

// ---------------------------------------------------------------------------
// K4: fusion + output heads.
// ---------------------------------------------------------------------------
__global__ void __launch_bounds__(64)
head_kernel(const float* __restrict__ local_emb, const float* __restrict__ glob,
            const float* __restrict__ q_emb,
            const float* __restrict__ fus_W, const float* __restrict__ fus_b,
            const float* __restrict__ out_W, const float* __restrict__ out_b,
            float* __restrict__ out)
{
    __shared__ float cat[128];
    __shared__ float fus[64];
    __shared__ float qv[64];
    const int b = blockIdx.x, d = threadIdx.x;
    cat[d]      = local_emb[(size_t)b * 64 + d];
    cat[64 + d] = glob[(size_t)b * 64 + d];
    qv[d]       = q_emb[(size_t)b * 64 + d];
    __syncthreads();
    float acc = fus_b[d];
    const float* fw = fus_W + (size_t)d * 128;
#pragma unroll 4
    for (int k = 0; k < 128; ++k) acc += cat[k] * fw[k];
    fus[d] = fmaxf(acc, 0.f);
    __syncthreads();
    float o0 = out_b[d], o1 = out_b[d];
    const float* ow = out_W + (size_t)d * 64;
#pragma unroll 4
    for (int k = 0; k < 64; ++k) { float ww = ow[k]; o0 += fus[k] * ww; o1 += qv[k] * ww; }
    out[(size_t)b * 64 + d] = o0;
    out[(size_t)BB * 64 + (size_t)b * 64 + d] = o1;
}

// ---------------------------------------------------------------------------
extern "C" void kernel_launch(void* const* d_in, const int* in_sizes, int n_in,
                              void* d_out, int out_size, void* d_ws, size_t ws_size,
                              hipStream_t stream)
{
    const int*   src_ids    = (const int*)d_in[0];
    const int*   dst_ids    = (const int*)d_in[1];
    const int*   l_nids     = (const int*)d_in[2];
    const int*   l_eids     = (const int*)d_in[3];
    const float* l_times    = (const float*)d_in[4];
    const int*   d_nids     = (const int*)d_in[5];
    const int*   d_eids     = (const int*)d_in[6];
    const float* d_times    = (const float*)d_in[7];
    const int*   retr       = (const int*)d_in[8];
    const float* node_raw   = (const float*)d_in[9];
    const float* edge_raw   = (const float*)d_in[10];
    const int*   pool_nodes = (const int*)d_in[11];
    const float* Wfeat  = (const float*)d_in[12];
    const float* bfeat  = (const float*)d_in[13];
    const float* Wedge  = (const float*)d_in[14];
    const float* bedge  = (const float*)d_in[15];
    const float* Wtime  = (const float*)d_in[16];
    const float* btime  = (const float*)d_in[17];
    const float* Wstruct= (const float*)d_in[18];
    const float* bstruct= (const float*)d_in[19];
    const float* ln_g   = (const float*)d_in[20];
    const float* ln_b   = (const float*)d_in[21];
    const float* gruL_Wih = (const float*)d_in[22];
    const float* gruL_Whh = (const float*)d_in[23];
    const float* gruL_bih = (const float*)d_in[24];
    const float* gruL_bhh = (const float*)d_in[25];
    const float* gruQ_Wih = (const float*)d_in[26];
    const float* gruQ_Whh = (const float*)d_in[27];
    const float* gruQ_bih = (const float*)d_in[28];
    const float* gruQ_bhh = (const float*)d_in[29];
    const float* gcn_W  = (const float*)d_in[30];
    const float* gcn_b  = (const float*)d_in[31];
    const float* fus_W  = (const float*)d_in[32];
    const float* fus_b  = (const float*)d_in[33];
    const float* out_W  = (const float*)d_in[34];
    const float* out_b  = (const float*)d_in[35];

    char* wsb = (char*)d_ws;
    auto alloc = [&](size_t bytes) -> void* {
        void* p = (void*)wsb;
        wsb += (bytes + 255) & ~(size_t)255;
        return p;
    };
    float*          proj_node = (float*)alloc((size_t)NN * DD * 4);
    float*          hgcn      = (float*)alloc((size_t)NN * DD * 4);
    unsigned short* TnL16     = (unsigned short*)alloc((size_t)NN * 192 * 2);
    unsigned short* TnQ16     = (unsigned short*)alloc((size_t)NN * 192 * 2);
    float*          cstL      = (float*)alloc(4096 * 4);
    float*          cstQ      = (float*)alloc(4096 * 4);
    unsigned*       whpL      = (unsigned*)alloc(192 * 32 * 4);
    unsigned*       whpQ      = (unsigned*)alloc(192 * 32 * 4);
    unsigned*       tpkL      = (unsigned*)alloc(192 * 8 * 4);
    unsigned*       tpkQ      = (unsigned*)alloc(192 * 8 * 4);
    unsigned*       wtpk      = (unsigned*)alloc(64 * 8 * 4);
    unsigned*       g01       = (unsigned*)alloc((size_t)2 * BB * LHH * 64 * 4);
    unsigned short* g2a       = (unsigned short*)alloc((size_t)2 * BB * LHH * 64 * 2);
    float*          local_emb = (float*)alloc((size_t)BB * DD * 4);
    float*          q_emb     = (float*)alloc((size_t)BB * DD * 4);
    float*          glob      = (float*)alloc((size_t)BB * DD * 4);

    dim3 g1((NN + 127) / 128);
    gemm_nt_kernel<FF><<<g1, 256, 0, stream>>>(node_raw, Wfeat, bfeat, proj_node, NN);

    consts_kernel<<<2, 192, 0, stream>>>(gruL_Wih, gruL_bih, gruL_Whh, cstL, whpL, tpkL,
                                         gruQ_Wih, gruQ_bih, gruQ_Whh, cstQ, whpQ, tpkQ,
                                         wtpk, ln_g, ln_b, Wedge, bedge, Wtime, btime,
                                         Wstruct, bstruct);

    tn_gemm_kernel<<<dim3(NN / 64, 2), 256, 0, stream>>>(proj_node, gruL_Wih, gruQ_Wih,
                                                         ln_g, TnL16, TnQ16);

    pre_kernel<<<2 * BB * 4, 64, 0, stream>>>(
        l_nids, l_eids, l_times, dst_ids,
        d_nids, d_eids, d_times, src_ids,
        node_raw, edge_raw, proj_node, TnL16, TnQ16, cstL, cstQ,
        tpkL, tpkQ, wtpk, gruL_bhh, gruQ_bhh,
        Wedge, bedge, Wtime, btime, Wstruct, bstruct,
        g01, g2a);

    gemm_nt_kernel<DD><<<g1, 256, 0, stream>>>(proj_node, gcn_W, nullptr, hgcn, NN);

    gru_lite_kernel<<<2 * BB, 64, 0, stream>>>(
        g01, g2a, whpL, whpQ, gruL_bhh, gruQ_bhh, local_emb, q_emb);

    graph_emb_kernel<<<BB, 512, 0, stream>>>(retr, pool_nodes, hgcn, gcn_b, glob);

    head_kernel<<<BB, 64, 0, stream>>>(local_emb, glob, q_emb,
        fus_W, fus_b, out_W, out_b, (float*)d_out);
}

// Round 12
// 295.819 us; speedup vs baseline: 1.2859x; 1.2859x over previous
//
#include <hip/hip_runtime.h>
#include <math.h>

#define NN 40000
#define FF 256
#define DD 64
#define LHH 200
#define BB 512
#define TDD 16
#define GE_HASH 1024

typedef _Float16 h2f __attribute__((ext_vector_type(2)));

__constant__ float TFREQ[16] = {
    1.0f,            0.48696753f,    0.23713737f,    0.115478195f,
    0.056234132f,    0.027384196f,   0.013335215f,   0.0064938162f,
    0.0031622776f,   0.0015399265f,  0.00074989421f, 0.00036517414f,
    0.00017782794f,  8.6596433e-05f, 4.2169650e-05f, 2.0535251e-05f
};

__device__ __forceinline__ float fd2(unsigned a, unsigned b, float c) {
    union { unsigned u; h2f h; } ua, ub;
    ua.u = a; ub.u = b;
    return __builtin_amdgcn_fdot2(ua.h, ub.h, c, false);
}
__device__ __forceinline__ unsigned packrn(float a, float b) {
    union { h2f h; unsigned u; } x;
    x.h.x = (_Float16)a; x.h.y = (_Float16)b;
    return x.u;
}
__device__ __forceinline__ unsigned short f16u(float a) {
    union { _Float16 h; unsigned short u; } x;
    x.h = (_Float16)a;
    return x.u;
}
__device__ __forceinline__ float h16f(unsigned short u) {
    union { unsigned short u; _Float16 h; } x;
    x.u = u;
    return (float)x.h;
}
__device__ __forceinline__ float f16lo(unsigned u) {
    union { unsigned u; h2f h; } x; x.u = u; return (float)x.h.x;
}
__device__ __forceinline__ float f16hi(unsigned u) {
    union { unsigned u; h2f h; } x; x.u = u; return (float)x.h.y;
}
__device__ __forceinline__ unsigned pkrtz_u(float a, float b) {
    auto pk = __builtin_amdgcn_cvt_pkrtz(a, b);
    union { decltype(pk) h; unsigned u; } x;
    x.h = pk;
    return x.u;
}
__device__ __forceinline__ float dpp_xor1(float v) {
    return __int_as_float(
        __builtin_amdgcn_mov_dpp(__float_as_int(v), 0xB1, 0xF, 0xF, true));
}
__device__ __forceinline__ unsigned rlu(unsigned v, int l) {
    return (unsigned)__builtin_amdgcn_readlane((int)v, l);
}
__device__ __forceinline__ float sigm(float x) {
    return __builtin_amdgcn_rcpf(1.f + __expf(-x));
}
__device__ __forceinline__ float tanh_f(float x) {
    float e = __expf(2.f * x);
    return 1.f - 2.f * __builtin_amdgcn_rcpf(e + 1.f);
}
__device__ __forceinline__ int hlookupf(const unsigned* hkey, const int* hslot, unsigned id)
{
    unsigned p = (id * 2654435761u) & (GE_HASH - 1);
    while (hkey[p] != id) p = (p + 1) & (GE_HASH - 1);
    return hslot[p];
}

// ---------------------------------------------------------------------------
// K1: C[n][0:64] = A[n][:] @ W[64][KDIM]^T + bias
// ---------------------------------------------------------------------------
template<int KDIM>
__global__ void __launch_bounds__(256)
gemm_nt_kernel(const float* __restrict__ A, const float* __restrict__ W,
               const float* __restrict__ bias, float* __restrict__ C, int Nrows)
{
    __shared__ __align__(16) float a_t[128][8];
    __shared__ __align__(16) float wt[8][64];
    const int tid = threadIdx.x;
    const int tx = tid & 15;
    const int ty = tid >> 4;
    const int n0 = blockIdx.x * 128;

    float4 acc[8];
#pragma unroll
    for (int r = 0; r < 8; ++r) acc[r] = make_float4(0.f, 0.f, 0.f, 0.f);

    for (int kc = 0; kc < KDIM; kc += 8) {
        __syncthreads();
        {
            int r = tid >> 1;
            int cc = (tid & 1) * 4;
            int n = n0 + r;
            float4 v = make_float4(0.f, 0.f, 0.f, 0.f);
            if (n < Nrows) v = *(const float4*)(A + (size_t)n * KDIM + kc + cc);
            *(float4*)&a_t[r][cc] = v;
        }
        {
            int m = tid >> 2;
            int f0 = (tid & 3) * 2;
            float2 v = *(const float2*)(W + (size_t)m * KDIM + kc + f0);
            wt[f0][m] = v.x; wt[f0 + 1][m] = v.y;
        }
        __syncthreads();
        float4 w4[8];
#pragma unroll
        for (int f = 0; f < 8; ++f) w4[f] = *(float4*)&wt[f][tx * 4];
#pragma unroll
        for (int rr = 0; rr < 8; ++rr) {
            int row = ty + rr * 16;
            float4 a0 = *(float4*)&a_t[row][0];
            float4 a1 = *(float4*)&a_t[row][4];
            float av[8] = {a0.x, a0.y, a0.z, a0.w, a1.x, a1.y, a1.z, a1.w};
#pragma unroll
            for (int f = 0; f < 8; ++f) {
                acc[rr].x += av[f] * w4[f].x;
                acc[rr].y += av[f] * w4[f].y;
                acc[rr].z += av[f] * w4[f].z;
                acc[rr].w += av[f] * w4[f].w;
            }
        }
    }
    float4 bv = make_float4(0.f, 0.f, 0.f, 0.f);
    if (bias) bv = *(const float4*)(bias + tx * 4);
#pragma unroll
    for (int rr = 0; rr < 8; ++rr) {
        int n = n0 + ty + rr * 16;
        if (n < Nrows) {
            float4 o = acc[rr];
            o.x += bv.x; o.y += bv.y; o.z += bv.z; o.w += bv.w;
            *(float4*)(C + (size_t)n * DD + tx * 4) = o;
        }
    }
}

// ---------------------------------------------------------------------------
// Tn16[n][j] = f16( sum_k proj[n][k] * Wih[j][k] * ln_g[k] ); grid.y = L/Q.
// ---------------------------------------------------------------------------
__global__ void __launch_bounds__(256)
tn_gemm_kernel(const float* __restrict__ proj,
               const float* __restrict__ WihL, const float* __restrict__ WihQ,
               const float* __restrict__ ln_g,
               unsigned short* __restrict__ TnL, unsigned short* __restrict__ TnQ)
{
    const float* Wih = blockIdx.y ? WihQ : WihL;
    unsigned short* Tn = blockIdx.y ? TnQ : TnL;
    __shared__ float wgT[64][193];
    __shared__ __align__(16) float4 at4[64][16];
    const int tid = threadIdx.x;
    const int n0 = blockIdx.x * 64;
    for (int i = tid; i < 192 * 64; i += 256) {
        int j = i >> 6, k = i & 63;
        wgT[k][j] = Wih[i] * ln_g[k];
    }
    for (int i = tid; i < 1024; i += 256) {
        int r = i >> 4, kc = i & 15;
        at4[r][kc] = ((const float4*)(proj + (size_t)(n0 + r) * DD))[kc];
    }
    __syncthreads();
    const int c = tid & 63, wv = tid >> 6;
    float acc0[16], acc1[16], acc2[16];
#pragma unroll
    for (int r = 0; r < 16; ++r) { acc0[r] = 0.f; acc1[r] = 0.f; acc2[r] = 0.f; }
    for (int kc = 0; kc < 16; ++kc) {
        float w0[4], w1[4], w2[4];
#pragma unroll
        for (int q = 0; q < 4; ++q) {
            w0[q] = wgT[kc * 4 + q][c];
            w1[q] = wgT[kc * 4 + q][64 + c];
            w2[q] = wgT[kc * 4 + q][128 + c];
        }
#pragma unroll
        for (int r = 0; r < 16; ++r) {
            float4 a = at4[wv * 16 + r][kc];
            acc0[r] += a.x * w0[0] + a.y * w0[1] + a.z * w0[2] + a.w * w0[3];
            acc1[r] += a.x * w1[0] + a.y * w1[1] + a.z * w1[2] + a.w * w1[3];
            acc2[r] += a.x * w2[0] + a.y * w2[1] + a.z * w2[2] + a.w * w2[3];
        }
    }
#pragma unroll
    for (int r = 0; r < 16; ++r) {
        size_t row = (size_t)(n0 + wv * 16 + r) * 192;
        Tn[row + c]       = f16u(acc0[r]);
        Tn[row + 64 + c]  = f16u(acc1[r]);
        Tn[row + 128 + c] = f16u(acc2[r]);
    }
}

// ---------------------------------------------------------------------------
// Per-gate-row constants out[21][192] + f16-packed Whh + packed time weights.
// ---------------------------------------------------------------------------
__global__ void __launch_bounds__(192)
consts_kernel(const float* __restrict__ WihL, const float* __restrict__ bihL,
              const float* __restrict__ WhhL, float* __restrict__ outL,
              unsigned* __restrict__ whpL, unsigned* __restrict__ tpkL,
              const float* __restrict__ WihQ, const float* __restrict__ bihQ,
              const float* __restrict__ WhhQ, float* __restrict__ outQ,
              unsigned* __restrict__ whpQ, unsigned* __restrict__ tpkQ,
              unsigned* __restrict__ wtpk,
              const float* __restrict__ ln_g, const float* __restrict__ ln_b,
              const float* __restrict__ Wedge, const float* __restrict__ bedge,
              const float* __restrict__ Wtime, const float* __restrict__ btime,
              const float* __restrict__ Wstruct, const float* __restrict__ bstruct)
{
    const float* Wih = blockIdx.x ? WihQ : WihL;
    const float* bih = blockIdx.x ? bihQ : bihL;
    const float* Whh = blockIdx.x ? WhhQ : WhhL;
    float* out = blockIdx.x ? outQ : outL;
    unsigned* whp = blockIdx.x ? whpQ : whpL;
    unsigned* tpk = blockIdx.x ? tpkQ : tpkL;
    const int j = threadIdx.x;
    float te = 0.f, tw = 0.f, t1 = 0.f, tb0 = 0.f, cc = 0.f;
    float tt[16];
#pragma unroll
    for (int t = 0; t < 16; ++t) tt[t] = 0.f;
    for (int k = 0; k < DD; ++k) {
        float wv = Wih[j * DD + k];
        float wg = wv * ln_g[k];
        te  += wg * Wedge[k];
        tw  += wg * Wstruct[k];
        t1  += wg;
        tb0 += wg * (bedge[k] + btime[k] + 2.f * bstruct[k]);
        cc  += wv * ln_b[k];
#pragma unroll
        for (int t = 0; t < 16; ++t) tt[t] += wg * Wtime[k * TDD + t];
    }
    out[0 * 192 + j] = te;
    out[1 * 192 + j] = tw;
    out[2 * 192 + j] = t1;
    out[3 * 192 + j] = tb0;
    out[4 * 192 + j] = cc + bih[j];
    for (int t = 0; t < 16; ++t) out[(5 + t) * 192 + j] = tt[t];
    for (int q = 0; q < 8; ++q)
        tpk[j * 8 + q] = packrn(tt[2 * q], tt[2 * q + 1]);
    if (blockIdx.x == 0 && j < 64)
        for (int q = 0; q < 8; ++q)
            wtpk[j * 8 + q] = packrn(Wtime[j * TDD + 2 * q], Wtime[j * TDD + 2 * q + 1]);
    for (int k2 = 0; k2 < 32; ++k2)
        whp[j * 32 + k2] = packrn(Whh[j * DD + 2 * k2], Whh[j * DD + 2 * k2 + 1]);
}

// ---------------------------------------------------------------------------
// PRE: compute folded gate pre-activations g0,g1,g2 for every (seq, l).
// ---------------------------------------------------------------------------
struct PS {
    int nid;
    float tn0, tn1, tn2, pv, e0, sk, t;
};

__global__ void __launch_bounds__(64)
pre_kernel(const int* __restrict__ nidsL, const int* __restrict__ eidsL,
           const float* __restrict__ timesL, const int* __restrict__ curL,
           const int* __restrict__ nidsQ, const int* __restrict__ eidsQ,
           const float* __restrict__ timesQ, const int* __restrict__ curQ,
           const float* __restrict__ node_raw, const float* __restrict__ edge_raw,
           const float* __restrict__ proj_node,
           const unsigned short* __restrict__ TnL, const unsigned short* __restrict__ TnQ,
           const float* __restrict__ cstL, const float* __restrict__ cstQ,
           const unsigned* __restrict__ tpkL, const unsigned* __restrict__ tpkQ,
           const unsigned* __restrict__ wtpk,
           const float* __restrict__ bhhL, const float* __restrict__ bhhQ,
           const float* __restrict__ Wedge, const float* __restrict__ bedge,
           const float* __restrict__ Wtime, const float* __restrict__ btime,
           const float* __restrict__ Wstruct, const float* __restrict__ bstruct,
           unsigned* __restrict__ g01out, unsigned short* __restrict__ g2out)
{
    const int bq = blockIdx.x;
    const int blk = bq >> 2, qq = bq & 3;
    const int g = blk >> 9, s = blk & 511;
    const int d = threadIdx.x;

    const int*            nids  = g ? nidsQ : nidsL;
    const int*            eids  = g ? eidsQ : eidsL;
    const float*          times = g ? timesQ : timesL;
    const int*            curp  = g ? curQ : curL;
    const unsigned short* Tn    = g ? TnQ : TnL;
    const float*          cst   = g ? cstQ : cstL;
    const unsigned*       tpk   = g ? tpkQ : tpkL;
    const float*          bhh   = g ? bhhQ : bhhL;

    unsigned tp0[8], tp1[8], tp2[8], wtp[8];
#pragma unroll
    for (int q4 = 0; q4 < 2; ++q4) {
        uint4 a = *(const uint4*)(tpk + (size_t)(0 * 64 + d) * 8 + 4 * q4);
        tp0[4*q4] = a.x; tp0[4*q4+1] = a.y; tp0[4*q4+2] = a.z; tp0[4*q4+3] = a.w;
        uint4 b = *(const uint4*)(tpk + (size_t)(1 * 64 + d) * 8 + 4 * q4);
        tp1[4*q4] = b.x; tp1[4*q4+1] = b.y; tp1[4*q4+2] = b.z; tp1[4*q4+3] = b.w;
        uint4 c = *(const uint4*)(tpk + (size_t)(2 * 64 + d) * 8 + 4 * q4);
        tp2[4*q4] = c.x; tp2[4*q4+1] = c.y; tp2[4*q4+2] = c.z; tp2[4*q4+3] = c.w;
        uint4 e = *(const uint4*)(wtpk + (size_t)d * 8 + 4 * q4);
        wtp[4*q4] = e.x; wtp[4*q4+1] = e.y; wtp[4*q4+2] = e.z; wtp[4*q4+3] = e.w;
    }
    const float TE0 = cst[0*192 + d], TE1 = cst[0*192 + 64 + d], TE2 = cst[0*192 + 128 + d];
    const float TW0 = cst[1*192 + d], TW1 = cst[1*192 + 64 + d], TW2 = cst[1*192 + 128 + d];
    const float T10 = cst[2*192 + d], T11 = cst[2*192 + 64 + d], T12 = cst[2*192 + 128 + d];
    const float TB0 = cst[3*192 + d], TB1 = cst[3*192 + 64 + d], TB2 = cst[3*192 + 128 + d];
    const float CC0 = cst[4*192 + d] + bhh[d];
    const float CC1 = cst[4*192 + 64 + d] + bhh[64 + d];
    const float CC2 = cst[4*192 + 128 + d];
    const float we_l = Wedge[d];
    const float ws_l = Wstruct[d];
    const float b0_l = bedge[d] + btime[d] + 2.f * bstruct[d];
    const float tfl  = TFREQ[d & 15];

    const int cur = curp[s];
    const int csk = (int)node_raw[(size_t)cur * FF];
    const int* nrow = nids + s * LHH;
    const int* erow = eids + s * LHH;
    const float* trow = times + s * LHH;
    const int lbase = qq * 50;

    auto GATH = [&](PS& P, int i) {
        int l = lbase + i;
        int nid = nrow[l];
        int eid = erow[l];
        P.nid = nid;
        const unsigned short* tb = Tn + (size_t)nid * 192;
        P.tn0 = h16f(tb[d]);
        P.tn1 = h16f(tb[64 + d]);
        P.tn2 = h16f(tb[128 + d]);
        P.pv  = proj_node[(size_t)nid * DD + d];
        P.e0  = edge_raw[(size_t)eid * 4];
        P.sk  = node_raw[(size_t)nid * FF];
        P.t   = trow[l];
    };

    auto EMIT = [&](const PS& P, int i) {
        float cv = __cosf(P.t * tfl);
        float cx = dpp_xor1(cv);
        unsigned cp = pkrtz_u(cv, cx);
        unsigned s0 = rlu(cp, 0),  s1 = rlu(cp, 2),  s2 = rlu(cp, 4),  s3 = rlu(cp, 6);
        unsigned s4 = rlu(cp, 8),  s5 = rlu(cp, 10), s6 = rlu(cp, 12), s7 = rlu(cp, 14);
        float tf = fd2(wtp[7], s7, fd2(wtp[6], s6, fd2(wtp[5], s5, fd2(wtp[4], s4, 0.f))));
        tf = fd2(wtp[3], s3, fd2(wtp[2], s2, fd2(wtp[1], s1, fd2(wtp[0], s0, tf))));
        float flg = ((P.nid == cur) ? 1.f : 0.f) + (((int)P.sk == csk) ? 1.f : 0.f);
        float f = P.pv + P.e0 * we_l + flg * ws_l + b0_l + tf;
        float mu = f;
#pragma unroll
        for (int off = 32; off; off >>= 1) mu += __shfl_xor(mu, off);
        mu *= (1.f / 64.f);
        float dv = f - mu, var = dv * dv;
#pragma unroll
        for (int off = 32; off; off >>= 1) var += __shfl_xor(var, off);
        float rs = rsqrtf(var * (1.f / 64.f) + 1e-5f);
        float c0 = fd2(tp0[7], s7, fd2(tp0[6], s6, fd2(tp0[5], s5, fd2(tp0[4], s4, 0.f))));
        c0 = fd2(tp0[3], s3, fd2(tp0[2], s2, fd2(tp0[1], s1, fd2(tp0[0], s0, c0))));
        float c1 = fd2(tp1[7], s7, fd2(tp1[6], s6, fd2(tp1[5], s5, fd2(tp1[4], s4, 0.f))));
        c1 = fd2(tp1[3], s3, fd2(tp1[2], s2, fd2(tp1[1], s1, fd2(tp1[0], s0, c1))));
        float c2 = fd2(tp2[7], s7, fd2(tp2[6], s6, fd2(tp2[5], s5, fd2(tp2[4], s4, 0.f))));
        c2 = fd2(tp2[3], s3, fd2(tp2[2], s2, fd2(tp2[1], s1, fd2(tp2[0], s0, c2))));
        float g0 = (c0 + P.tn0 + P.e0 * TE0 + flg * TW0 + TB0 - mu * T10) * rs + CC0;
        float g1 = (c1 + P.tn1 + P.e0 * TE1 + flg * TW1 + TB1 - mu * T11) * rs + CC1;
        float g2 = (c2 + P.tn2 + P.e0 * TE2 + flg * TW2 + TB2 - mu * T12) * rs + CC2;
        size_t pos = ((size_t)blk * LHH + (lbase + i)) * 64 + d;
        g01out[pos] = packrn(g0, g1);
        g2out[pos] = f16u(g2);
    };

    PS Pc, Pn;
    GATH(Pc, 0);
    for (int i = 0; i < 50; ++i) {
        int inext = (i + 1 < 50) ? i + 1 : 49;
        GATH(Pn, inext);
        EMIT(Pc, i);
        Pc = Pn;
    }
}

// ---------------------------------------------------------------------------
// GRU-lite: ONE wave per sequence; only the h-recurrence.
// ---------------------------------------------------------------------------
__global__ void __launch_bounds__(64) __attribute__((amdgpu_waves_per_eu(1, 1)))
gru_lite_kernel(const unsigned* __restrict__ g01, const unsigned short* __restrict__ g2a,
                const unsigned* __restrict__ whpL, const unsigned* __restrict__ whpQ,
                const float* __restrict__ bhhL, const float* __restrict__ bhhQ,
                float* __restrict__ embL, float* __restrict__ embQ)
{
    const int blk = blockIdx.x;
    const int g = blk >> 9, s = blk & 511;
    const int d = threadIdx.x;

    const unsigned* whp = g ? whpQ : whpL;
    const float*    bhh = g ? bhhQ : bhhL;
    float*          emb = g ? embQ : embL;

    unsigned w0[32], w1[32], w2[32];
    {
        const unsigned* p0 = whp + (size_t)d * 32;
        const unsigned* p1 = whp + (size_t)(64 + d) * 32;
        const unsigned* p2 = whp + (size_t)(128 + d) * 32;
#pragma unroll
        for (int q4 = 0; q4 < 8; ++q4) {
            uint4 a = *(const uint4*)(p0 + 4 * q4);
            w0[4*q4] = a.x; w0[4*q4+1] = a.y; w0[4*q4+2] = a.z; w0[4*q4+3] = a.w;
            uint4 b = *(const uint4*)(p1 + 4 * q4);
            w1[4*q4] = b.x; w1[4*q4+1] = b.y; w1[4*q4+2] = b.z; w1[4*q4+3] = b.w;
            uint4 c = *(const uint4*)(p2 + 4 * q4);
            w2[4*q4] = c.x; w2[4*q4+1] = c.y; w2[4*q4+2] = c.z; w2[4*q4+3] = c.w;
        }
    }
#pragma unroll
    for (int i = 0; i < 32; ++i) {
        asm volatile("" : "+v"(w0[i]));
        asm volatile("" : "+v"(w1[i]));
        asm volatile("" : "+v"(w2[i]));
    }
    const float BH2 = bhh[128 + d];

    const unsigned* p01 = g01 + (size_t)blk * LHH * 64 + d;
    const unsigned short* p2 = g2a + (size_t)blk * LHH * 64 + d;

    float h = 0.f;

    auto COMPUTE = [&](unsigned pk01, unsigned pk2) {
        float g0 = f16lo(pk01), g1 = f16hi(pk01);
        float g2 = h16f((unsigned short)pk2);
        float hx = dpp_xor1(h);
        unsigned hpu = pkrtz_u(h, hx);
        float a0 = 0.f, a1 = 0.f, a2 = 0.f, e0 = 0.f, e1 = 0.f, e2 = 0.f;
#pragma unroll
        for (int q = 0; q < 32; q += 2) {
            unsigned sa = rlu(hpu, 2 * q);
            unsigned sb = rlu(hpu, 2 * q + 2);
            a0 = fd2(w0[q], sa, a0);
            a1 = fd2(w1[q], sa, a1);
            a2 = fd2(w2[q], sa, a2);
            e0 = fd2(w0[q+1], sb, e0);
            e1 = fd2(w1[q+1], sb, e1);
            e2 = fd2(w2[q+1], sb, e2);
        }
        float mv0 = a0 + e0, mv1 = a1 + e1, mv2 = a2 + e2;
        float r = sigm(g0 + mv0);
        float z = sigm(g1 + mv1);
        float n = tanh_f(g2 + r * (mv2 + BH2));
        h = (1.f - z) * n + z * h;
    };

    unsigned A01[4], A2[4], B01[4], B2[4];
#pragma unroll
    for (int i = 0; i < 4; ++i) {
        A01[i] = p01[(size_t)i * 64];
        A2[i]  = p2[(size_t)i * 64];
    }
    for (int l = 0; l < LHH; l += 8) {
#pragma unroll
        for (int i = 0; i < 4; ++i) {
            int ll = l + 4 + i;
            B01[i] = p01[(size_t)ll * 64];
            B2[i]  = p2[(size_t)ll * 64];
        }
#pragma unroll
        for (int i = 0; i < 4; ++i) COMPUTE(A01[i], A2[i]);
#pragma unroll
        for (int i = 0; i < 4; ++i) {
            int ll = l + 8 + i;
            if (ll > LHH - 1) ll = LHH - 1;
            A01[i] = p01[(size_t)ll * 64];
            A2[i]  = p2[(size_t)ll * 64];
        }
#pragma unroll
        for (int i = 0; i < 4; ++i) COMPUTE(B01[i], B2[i]);
    }
    emb[(size_t)s * DD + d] = h;
}

// ---------------------------------------------------------------------------
// K3a: dedup + CSR build. One block per batch row. Writes:
//   slot_idG[b][400], disG[b][400], startG[b][404] (U+1 valid), adjG[b][800],
//   Ub[b].
// ---------------------------------------------------------------------------
__global__ void __launch_bounds__(512)
dedup_kernel(const int* __restrict__ retrieved, const int* __restrict__ pool_nodes,
             int* __restrict__ slot_idG, float* __restrict__ disG,
             unsigned* __restrict__ startG, unsigned short* __restrict__ adjG,
             int* __restrict__ Ub)
{
    __shared__ unsigned hkey[GE_HASH];
    __shared__ int hslot[GE_HASH];
    __shared__ unsigned ekey[GE_HASH];
    __shared__ int ids[400];
    __shared__ int slot_id[400];
    __shared__ unsigned deg[400];
    __shared__ float dis[400];
    __shared__ unsigned elist[400];
    __shared__ unsigned scanA[400], scanB[400];
    __shared__ int cursor[400];
    __shared__ unsigned short adjS[800];
    __shared__ int pids[8];
    __shared__ int cntU, cntE;

    const int b = blockIdx.x;
    const int tid = threadIdx.x;

    if (tid < 8) pids[tid] = retrieved[b * 8 + tid];
    if (tid == 0) { cntU = 0; cntE = 0; }
    for (int i = tid; i < GE_HASH; i += 512) { hkey[i] = 0u; ekey[i] = 0u; }
    if (tid < 400) deg[tid] = 0u;
    __syncthreads();

    if (tid < 400) {
        int k = tid / 50, p = tid % 50;
        ids[tid] = pool_nodes[(size_t)pids[k] * 50 + p];
    }
    __syncthreads();

    if (tid < 400) {
        int idi = ids[tid];
        if (idi > 0) {
            unsigned id = (unsigned)idi;
            unsigned p = (id * 2654435761u) & (GE_HASH - 1);
            while (true) {
                unsigned old = atomicCAS(&hkey[p], 0u, id);
                if (old == 0u) {
                    int s = atomicAdd(&cntU, 1);
                    hslot[p] = s; slot_id[s] = idi;
                    break;
                }
                if (old == id) break;
                p = (p + 1) & (GE_HASH - 1);
            }
        }
    }
    __syncthreads();

    if (tid < 8 * 49) {
        int k = tid / 49, p = tid % 49;
        int u = ids[k * 50 + p], v = ids[k * 50 + p + 1];
        if (u > 0 && v > 0) {
            unsigned a = (unsigned)min(u, v), bb = (unsigned)max(u, v);
            unsigned key = a * 40000u + bb;
            unsigned p2 = (key * 2654435761u) & (GE_HASH - 1);
            while (true) {
                unsigned old = atomicCAS(&ekey[p2], 0u, key);
                if (old == 0u) {
                    int su = hlookupf(hkey, hslot, a);
                    int sv = hlookupf(hkey, hslot, bb);
                    int e = atomicAdd(&cntE, 1);
                    elist[e] = ((unsigned)su << 16) | (unsigned)sv;
                    atomicAdd(&deg[su], 1u);
                    atomicAdd(&deg[sv], 1u);
                    break;
                }
                if (old == key) break;
                p2 = (p2 + 1) & (GE_HASH - 1);
            }
        }
    }
    __syncthreads();

    const int U = cntU, EC = cntE;
    if (tid < 400) {
        dis[tid] = rsqrtf((float)deg[tid] + 1.0f);
        scanA[tid] = deg[tid];
    }
    __syncthreads();

    // inclusive prefix scan over 400 (Hillis-Steele, ping-pong)
    unsigned* src = scanA;
    unsigned* dst = scanB;
    for (int off = 1; off < 400; off <<= 1) {
        if (tid < 400)
            dst[tid] = src[tid] + ((tid >= off) ? src[tid - off] : 0u);
        __syncthreads();
        unsigned* t = src; src = dst; dst = t;
    }
    // exclusive start + cursor
    if (tid < 400) {
        unsigned st = src[tid] - deg[tid];
        cursor[tid] = (int)st;
        if (tid < U) startG[(size_t)b * 404 + tid] = st;
    }
    if (tid == 0) {
        startG[(size_t)b * 404 + U] = (U > 0) ? src[U - 1] : 0u;
        Ub[b] = U;
    }
    __syncthreads();

    // scatter adjacency (both directions)
    if (tid < EC) {
        unsigned pk = elist[tid];
        int su = (int)(pk >> 16), sv = (int)(pk & 0xffffu);
        int pu = atomicAdd(&cursor[su], 1);
        adjS[pu] = (unsigned short)sv;
        int pv = atomicAdd(&cursor[sv], 1);
        adjS[pv] = (unsigned short)su;
    }
    __syncthreads();

    // dump to global
    if (tid < 400) {
        slot_idG[(size_t)b * 400 + tid] = (tid < U) ? slot_id[tid] : 0;
        disG[(size_t)b * 400 + tid] = dis[tid];
    }
    for (int i = tid; i < 800; i += 512) {
        unsigned tot = (U > 0) ? src[U - 1] : 0u;   // 2*EC
        adjG[(size_t)b * 800 + i] = (i < (int)tot) ? adjS[i] : (unsigned short)0;
    }
}

// ---------------------------------------------------------------------------
// K3b: slot-parallel GCN aggregate + relu + partial sum. grid (BB, 4).
// No atomics, no big LDS; deep TLP (tiny LDS -> many blocks/CU).
// ---------------------------------------------------------------------------
__global__ void __launch_bounds__(256)
gcn_agg_kernel(const float* __restrict__ hgcn, const float* __restrict__ gcn_b,
               const int* __restrict__ slot_idG, const float* __restrict__ disG,
               const unsigned* __restrict__ startG, const unsigned short* __restrict__ adjG,
               const int* __restrict__ Ub, float* __restrict__ part)
{
    __shared__ int sidS[400];
    __shared__ float disS[400];
    __shared__ unsigned stS[404];
    __shared__ unsigned short adjS[800];
    __shared__ float red[4][64];

    const int b = blockIdx.x, q = blockIdx.y;
    const int tid = threadIdx.x;
    const int lane = tid & 63, w = tid >> 6;
    const int U = Ub[b];

    for (int i = tid; i < 400; i += 256) {
        sidS[i] = slot_idG[(size_t)b * 400 + i];
        disS[i] = disG[(size_t)b * 400 + i];
    }
    for (int i = tid; i < 404; i += 256) stS[i] = startG[(size_t)b * 404 + i];
    for (int i = tid; i < 800; i += 256) adjS[i] = adjG[(size_t)b * 800 + i];
    __syncthreads();

    const float gb = gcn_b[lane];
    float acc = 0.f;

    for (int s = q * 4 + w; s < U; s += 16) {
        int nid = sidS[s];
        float ds = disS[s];
        float v = fmaf(ds * ds, hgcn[(size_t)nid * 64 + lane], gb);
        int a0 = (int)stS[s];
        int cnt = (int)stS[s + 1] - a0;
        for (int e0 = 0; e0 < cnt; e0 += 4) {
            float hv[4], nr[4];
#pragma unroll
            for (int j = 0; j < 4; ++j) {
                int e = e0 + j;
                int ec = (e < cnt) ? e : cnt - 1;
                int o = adjS[a0 + ec];
                nr[j] = (e < cnt) ? ds * disS[o] : 0.f;
                hv[j] = hgcn[(size_t)sidS[o] * 64 + lane];
            }
            v += nr[0] * hv[0] + nr[1] * hv[1] + nr[2] * hv[2] + nr[3] * hv[3];
        }
        acc += fmaxf(v, 0.f);
    }

    red[w][lane] = acc;
    __syncthreads();
    if (tid < 64)
        part[((size_t)b * 4 + q) * 64 + tid] =
            red[0][tid] + red[1][tid] + red[2][tid] + red[3][tid];
}

// ---------------------------------------------------------------------------
// K4: fusion + output heads (consumes GCN partials).
// ---------------------------------------------------------------------------
__global__ void __launch_bounds__(64)
head_kernel(const float* __restrict__ local_emb, const float* __restrict__ part,
            const int* __restrict__ Ub, const float* __restrict__ q_emb,
            const float* __restrict__ fus_W, const float* __restrict__ fus_b,
            const float* __restrict__ out_W, const float* __restrict__ out_b,
            float* __restrict__ out)
{
    __shared__ float cat[128];
    __shared__ float fus[64];
    __shared__ float qv[64];
    const int b = blockIdx.x, d = threadIdx.x;
    cat[d] = local_emb[(size_t)b * 64 + d];
    {
        const float* pb = part + (size_t)b * 4 * 64;
        float gsum = pb[d] + pb[64 + d] + pb[128 + d] + pb[192 + d];
        cat[64 + d] = gsum / (float)max(Ub[b], 1);
    }
    qv[d] = q_emb[(size_t)b * 64 + d];
    __syncthreads();
    float acc = fus_b[d];
    const float* fw = fus_W + (size_t)d * 128;
#pragma unroll 4
    for (int k = 0; k < 128; ++k) acc += cat[k] * fw[k];
    fus[d] = fmaxf(acc, 0.f);
    __syncthreads();
    float o0 = out_b[d], o1 = out_b[d];
    const float* ow = out_W + (size_t)d * 64;
#pragma unroll 4
    for (int k = 0; k < 64; ++k) { float ww = ow[k]; o0 += fus[k] * ww; o1 += qv[k] * ww; }
    out[(size_t)b * 64 + d] = o0;
    out[(size_t)BB * 64 + (size_t)b * 64 + d] = o1;
}

// ---------------------------------------------------------------------------
extern "C" void kernel_launch(void* const* d_in, const int* in_sizes, int n_in,
                              void* d_out, int out_size, void* d_ws, size_t ws_size,
                              hipStream_t stream)
{
    const int*   src_ids    = (const int*)d_in[0];
    const int*   dst_ids    = (const int*)d_in[1];
    const int*   l_nids     = (const int*)d_in[2];
    const int*   l_eids     = (const int*)d_in[3];
    const float* l_times    = (const float*)d_in[4];
    const int*   d_nids     = (const int*)d_in[5];
    const int*   d_eids     = (const int*)d_in[6];
    const float* d_times    = (const float*)d_in[7];
    const int*   retr       = (const int*)d_in[8];
    const float* node_raw   = (const float*)d_in[9];
    const float* edge_raw   = (const float*)d_in[10];
    const int*   pool_nodes = (const int*)d_in[11];
    const float* Wfeat  = (const float*)d_in[12];
    const float* bfeat  = (const float*)d_in[13];
    const float* Wedge  = (const float*)d_in[14];
    const float* bedge  = (const float*)d_in[15];
    const float* Wtime  = (const float*)d_in[16];
    const float* btime  = (const float*)d_in[17];
    const float* Wstruct= (const float*)d_in[18];
    const float* bstruct= (const float*)d_in[19];
    const float* ln_g   = (const float*)d_in[20];
    const float* ln_b   = (const float*)d_in[21];
    const float* gruL_Wih = (const float*)d_in[22];
    const float* gruL_Whh = (const float*)d_in[23];
    const float* gruL_bih = (const float*)d_in[24];
    const float* gruL_bhh = (const float*)d_in[25];
    const float* gruQ_Wih = (const float*)d_in[26];
    const float* gruQ_Whh = (const float*)d_in[27];
    const float* gruQ_bih = (const float*)d_in[28];
    const float* gruQ_bhh = (const float*)d_in[29];
    const float* gcn_W  = (const float*)d_in[30];
    const float* gcn_b  = (const float*)d_in[31];
    const float* fus_W  = (const float*)d_in[32];
    const float* fus_b  = (const float*)d_in[33];
    const float* out_W  = (const float*)d_in[34];
    const float* out_b  = (const float*)d_in[35];

    char* wsb = (char*)d_ws;
    auto alloc = [&](size_t bytes) -> void* {
        void* p = (void*)wsb;
        wsb += (bytes + 255) & ~(size_t)255;
        return p;
    };
    float*          proj_node = (float*)alloc((size_t)NN * DD * 4);
    float*          hgcn      = (float*)alloc((size_t)NN * DD * 4);
    unsigned short* TnL16     = (unsigned short*)alloc((size_t)NN * 192 * 2);
    unsigned short* TnQ16     = (unsigned short*)alloc((size_t)NN * 192 * 2);
    float*          cstL      = (float*)alloc(4096 * 4);
    float*          cstQ      = (float*)alloc(4096 * 4);
    unsigned*       whpL      = (unsigned*)alloc(192 * 32 * 4);
    unsigned*       whpQ      = (unsigned*)alloc(192 * 32 * 4);
    unsigned*       tpkL      = (unsigned*)alloc(192 * 8 * 4);
    unsigned*       tpkQ      = (unsigned*)alloc(192 * 8 * 4);
    unsigned*       wtpk      = (unsigned*)alloc(64 * 8 * 4);
    unsigned*       g01       = (unsigned*)alloc((size_t)2 * BB * LHH * 64 * 4);
    unsigned short* g2a       = (unsigned short*)alloc((size_t)2 * BB * LHH * 64 * 2);
    int*            slot_idG  = (int*)alloc((size_t)BB * 400 * 4);
    float*          disG      = (float*)alloc((size_t)BB * 400 * 4);
    unsigned*       startG    = (unsigned*)alloc((size_t)BB * 404 * 4);
    unsigned short* adjG      = (unsigned short*)alloc((size_t)BB * 800 * 2);
    int*            Ubuf      = (int*)alloc((size_t)BB * 4);
    float*          part      = (float*)alloc((size_t)BB * 4 * 64 * 4);
    float*          local_emb = (float*)alloc((size_t)BB * DD * 4);
    float*          q_emb     = (float*)alloc((size_t)BB * DD * 4);

    dim3 g1((NN + 127) / 128);
    gemm_nt_kernel<FF><<<g1, 256, 0, stream>>>(node_raw, Wfeat, bfeat, proj_node, NN);

    consts_kernel<<<2, 192, 0, stream>>>(gruL_Wih, gruL_bih, gruL_Whh, cstL, whpL, tpkL,
                                         gruQ_Wih, gruQ_bih, gruQ_Whh, cstQ, whpQ, tpkQ,
                                         wtpk, ln_g, ln_b, Wedge, bedge, Wtime, btime,
                                         Wstruct, bstruct);

    tn_gemm_kernel<<<dim3(NN / 64, 2), 256, 0, stream>>>(proj_node, gruL_Wih, gruQ_Wih,
                                                         ln_g, TnL16, TnQ16);

    dedup_kernel<<<BB, 512, 0, stream>>>(retr, pool_nodes, slot_idG, disG,
                                         startG, adjG, Ubuf);

    pre_kernel<<<2 * BB * 4, 64, 0, stream>>>(
        l_nids, l_eids, l_times, dst_ids,
        d_nids, d_eids, d_times, src_ids,
        node_raw, edge_raw, proj_node, TnL16, TnQ16, cstL, cstQ,
        tpkL, tpkQ, wtpk, gruL_bhh, gruQ_bhh,
        Wedge, bedge, Wtime, btime, Wstruct, bstruct,
        g01, g2a);

    gemm_nt_kernel<DD><<<g1, 256, 0, stream>>>(proj_node, gcn_W, nullptr, hgcn, NN);

    gru_lite_kernel<<<2 * BB, 64, 0, stream>>>(
        g01, g2a, whpL, whpQ, gruL_bhh, gruQ_bhh, local_emb, q_emb);

    gcn_agg_kernel<<<dim3(BB, 4), 256, 0, stream>>>(
        hgcn, gcn_b, slot_idG, disG, startG, adjG, Ubuf, part);

    head_kernel<<<BB, 64, 0, stream>>>(local_emb, part, Ubuf, q_emb,
        fus_W, fus_b, out_W, out_b, (float*)d_out);
}

// Round 13
// 291.964 us; speedup vs baseline: 1.3029x; 1.0132x over previous
//
#include <hip/hip_runtime.h>
#include <math.h>

#define NN 40000
#define FF 256
#define DD 64
#define LHH 200
#define BB 512
#define TDD 16
#define GE_HASH 1024

typedef _Float16 h2f __attribute__((ext_vector_type(2)));

__constant__ float TFREQ[16] = {
    1.0f,            0.48696753f,    0.23713737f,    0.115478195f,
    0.056234132f,    0.027384196f,   0.013335215f,   0.0064938162f,
    0.0031622776f,   0.0015399265f,  0.00074989421f, 0.00036517414f,
    0.00017782794f,  8.6596433e-05f, 4.2169650e-05f, 2.0535251e-05f
};

__device__ __forceinline__ float fd2(unsigned a, unsigned b, float c) {
    union { unsigned u; h2f h; } ua, ub;
    ua.u = a; ub.u = b;
    return __builtin_amdgcn_fdot2(ua.h, ub.h, c, false);
}
__device__ __forceinline__ unsigned packrn(float a, float b) {
    union { h2f h; unsigned u; } x;
    x.h.x = (_Float16)a; x.h.y = (_Float16)b;
    return x.u;
}
__device__ __forceinline__ unsigned short f16u(float a) {
    union { _Float16 h; unsigned short u; } x;
    x.h = (_Float16)a;
    return x.u;
}
__device__ __forceinline__ float h16f(unsigned short u) {
    union { unsigned short u; _Float16 h; } x;
    x.u = u;
    return (float)x.h;
}
__device__ __forceinline__ float f16lo(unsigned u) {
    union { unsigned u; h2f h; } x; x.u = u; return (float)x.h.x;
}
__device__ __forceinline__ float f16hi(unsigned u) {
    union { unsigned u; h2f h; } x; x.u = u; return (float)x.h.y;
}
__device__ __forceinline__ unsigned pkrtz_u(float a, float b) {
    auto pk = __builtin_amdgcn_cvt_pkrtz(a, b);
    union { decltype(pk) h; unsigned u; } x;
    x.h = pk;
    return x.u;
}
__device__ __forceinline__ float dpp_xor1(float v) {
    return __int_as_float(
        __builtin_amdgcn_mov_dpp(__float_as_int(v), 0xB1, 0xF, 0xF, true));
}
__device__ __forceinline__ unsigned rlu(unsigned v, int l) {
    return (unsigned)__builtin_amdgcn_readlane((int)v, l);
}
__device__ __forceinline__ float sigm(float x) {
    return __builtin_amdgcn_rcpf(1.f + __expf(-x));
}
__device__ __forceinline__ float tanh_f(float x) {
    float e = __expf(2.f * x);
    return 1.f - 2.f * __builtin_amdgcn_rcpf(e + 1.f);
}
__device__ __forceinline__ int hlookupf(const unsigned* hkey, const int* hslot, unsigned id)
{
    unsigned p = (id * 2654435761u) & (GE_HASH - 1);
    while (hkey[p] != id) p = (p + 1) & (GE_HASH - 1);
    return hslot[p];
}

// ---------------------------------------------------------------------------
// K1: C[n][0:64] = A[n][:] @ W[64][KDIM]^T + bias
// ---------------------------------------------------------------------------
template<int KDIM>
__global__ void __launch_bounds__(256)
gemm_nt_kernel(const float* __restrict__ A, const float* __restrict__ W,
               const float* __restrict__ bias, float* __restrict__ C, int Nrows)
{
    __shared__ __align__(16) float a_t[128][8];
    __shared__ __align__(16) float wt[8][64];
    const int tid = threadIdx.x;
    const int tx = tid & 15;
    const int ty = tid >> 4;
    const int n0 = blockIdx.x * 128;

    float4 acc[8];
#pragma unroll
    for (int r = 0; r < 8; ++r) acc[r] = make_float4(0.f, 0.f, 0.f, 0.f);

    for (int kc = 0; kc < KDIM; kc += 8) {
        __syncthreads();
        {
            int r = tid >> 1;
            int cc = (tid & 1) * 4;
            int n = n0 + r;
            float4 v = make_float4(0.f, 0.f, 0.f, 0.f);
            if (n < Nrows) v = *(const float4*)(A + (size_t)n * KDIM + kc + cc);
            *(float4*)&a_t[r][cc] = v;
        }
        {
            int m = tid >> 2;
            int f0 = (tid & 3) * 2;
            float2 v = *(const float2*)(W + (size_t)m * KDIM + kc + f0);
            wt[f0][m] = v.x; wt[f0 + 1][m] = v.y;
        }
        __syncthreads();
        float4 w4[8];
#pragma unroll
        for (int f = 0; f < 8; ++f) w4[f] = *(float4*)&wt[f][tx * 4];
#pragma unroll
        for (int rr = 0; rr < 8; ++rr) {
            int row = ty + rr * 16;
            float4 a0 = *(float4*)&a_t[row][0];
            float4 a1 = *(float4*)&a_t[row][4];
            float av[8] = {a0.x, a0.y, a0.z, a0.w, a1.x, a1.y, a1.z, a1.w};
#pragma unroll
            for (int f = 0; f < 8; ++f) {
                acc[rr].x += av[f] * w4[f].x;
                acc[rr].y += av[f] * w4[f].y;
                acc[rr].z += av[f] * w4[f].z;
                acc[rr].w += av[f] * w4[f].w;
            }
        }
    }
    float4 bv = make_float4(0.f, 0.f, 0.f, 0.f);
    if (bias) bv = *(const float4*)(bias + tx * 4);
#pragma unroll
    for (int rr = 0; rr < 8; ++rr) {
        int n = n0 + ty + rr * 16;
        if (n < Nrows) {
            float4 o = acc[rr];
            o.x += bv.x; o.y += bv.y; o.z += bv.z; o.w += bv.w;
            *(float4*)(C + (size_t)n * DD + tx * 4) = o;
        }
    }
}

// ---------------------------------------------------------------------------
// Tn16[n][j] = f16( sum_k proj[n][k] * Wih[j][k] * ln_g[k] ); grid.y = L/Q.
// ---------------------------------------------------------------------------
__global__ void __launch_bounds__(256)
tn_gemm_kernel(const float* __restrict__ proj,
               const float* __restrict__ WihL, const float* __restrict__ WihQ,
               const float* __restrict__ ln_g,
               unsigned short* __restrict__ TnL, unsigned short* __restrict__ TnQ)
{
    const float* Wih = blockIdx.y ? WihQ : WihL;
    unsigned short* Tn = blockIdx.y ? TnQ : TnL;
    __shared__ float wgT[64][193];
    __shared__ __align__(16) float4 at4[64][16];
    const int tid = threadIdx.x;
    const int n0 = blockIdx.x * 64;
    for (int i = tid; i < 192 * 64; i += 256) {
        int j = i >> 6, k = i & 63;
        wgT[k][j] = Wih[i] * ln_g[k];
    }
    for (int i = tid; i < 1024; i += 256) {
        int r = i >> 4, kc = i & 15;
        at4[r][kc] = ((const float4*)(proj + (size_t)(n0 + r) * DD))[kc];
    }
    __syncthreads();
    const int c = tid & 63, wv = tid >> 6;
    float acc0[16], acc1[16], acc2[16];
#pragma unroll
    for (int r = 0; r < 16; ++r) { acc0[r] = 0.f; acc1[r] = 0.f; acc2[r] = 0.f; }
    for (int kc = 0; kc < 16; ++kc) {
        float w0[4], w1[4], w2[4];
#pragma unroll
        for (int q = 0; q < 4; ++q) {
            w0[q] = wgT[kc * 4 + q][c];
            w1[q] = wgT[kc * 4 + q][64 + c];
            w2[q] = wgT[kc * 4 + q][128 + c];
        }
#pragma unroll
        for (int r = 0; r < 16; ++r) {
            float4 a = at4[wv * 16 + r][kc];
            acc0[r] += a.x * w0[0] + a.y * w0[1] + a.z * w0[2] + a.w * w0[3];
            acc1[r] += a.x * w1[0] + a.y * w1[1] + a.z * w1[2] + a.w * w1[3];
            acc2[r] += a.x * w2[0] + a.y * w2[1] + a.z * w2[2] + a.w * w2[3];
        }
    }
#pragma unroll
    for (int r = 0; r < 16; ++r) {
        size_t row = (size_t)(n0 + wv * 16 + r) * 192;
        Tn[row + c]       = f16u(acc0[r]);
        Tn[row + 64 + c]  = f16u(acc1[r]);
        Tn[row + 128 + c] = f16u(acc2[r]);
    }
}

// ---------------------------------------------------------------------------
// Per-gate-row constants out[21][192] + f16-packed Whh + packed time weights.
// ---------------------------------------------------------------------------
__global__ void __launch_bounds__(192)
consts_kernel(const float* __restrict__ WihL, const float* __restrict__ bihL,
              const float* __restrict__ WhhL, float* __restrict__ outL,
              unsigned* __restrict__ whpL, unsigned* __restrict__ tpkL,
              const float* __restrict__ WihQ, const float* __restrict__ bihQ,
              const float* __restrict__ WhhQ, float* __restrict__ outQ,
              unsigned* __restrict__ whpQ, unsigned* __restrict__ tpkQ,
              unsigned* __restrict__ wtpk,
              const float* __restrict__ ln_g, const float* __restrict__ ln_b,
              const float* __restrict__ Wedge, const float* __restrict__ bedge,
              const float* __restrict__ Wtime, const float* __restrict__ btime,
              const float* __restrict__ Wstruct, const float* __restrict__ bstruct)
{
    const float* Wih = blockIdx.x ? WihQ : WihL;
    const float* bih = blockIdx.x ? bihQ : bihL;
    const float* Whh = blockIdx.x ? WhhQ : WhhL;
    float* out = blockIdx.x ? outQ : outL;
    unsigned* whp = blockIdx.x ? whpQ : whpL;
    unsigned* tpk = blockIdx.x ? tpkQ : tpkL;
    const int j = threadIdx.x;
    float te = 0.f, tw = 0.f, t1 = 0.f, tb0 = 0.f, cc = 0.f;
    float tt[16];
#pragma unroll
    for (int t = 0; t < 16; ++t) tt[t] = 0.f;
    for (int k = 0; k < DD; ++k) {
        float wv = Wih[j * DD + k];
        float wg = wv * ln_g[k];
        te  += wg * Wedge[k];
        tw  += wg * Wstruct[k];
        t1  += wg;
        tb0 += wg * (bedge[k] + btime[k] + 2.f * bstruct[k]);
        cc  += wv * ln_b[k];
#pragma unroll
        for (int t = 0; t < 16; ++t) tt[t] += wg * Wtime[k * TDD + t];
    }
    out[0 * 192 + j] = te;
    out[1 * 192 + j] = tw;
    out[2 * 192 + j] = t1;
    out[3 * 192 + j] = tb0;
    out[4 * 192 + j] = cc + bih[j];
    for (int t = 0; t < 16; ++t) out[(5 + t) * 192 + j] = tt[t];
    for (int q = 0; q < 8; ++q)
        tpk[j * 8 + q] = packrn(tt[2 * q], tt[2 * q + 1]);
    if (blockIdx.x == 0 && j < 64)
        for (int q = 0; q < 8; ++q)
            wtpk[j * 8 + q] = packrn(Wtime[j * TDD + 2 * q], Wtime[j * TDD + 2 * q + 1]);
    for (int k2 = 0; k2 < 32; ++k2)
        whp[j * 32 + k2] = packrn(Whh[j * DD + 2 * k2], Whh[j * DD + 2 * k2 + 1]);
}

// ---------------------------------------------------------------------------
// PRE: folded gate pre-activations. 25 positions/wave (8192 waves = full
// occupancy) with depth-2 gather pipeline.
// ---------------------------------------------------------------------------
struct PS {
    int nid;
    float tn0, tn1, tn2, pv, e0, sk, t;
};

__global__ void __launch_bounds__(64)
pre_kernel(const int* __restrict__ nidsL, const int* __restrict__ eidsL,
           const float* __restrict__ timesL, const int* __restrict__ curL,
           const int* __restrict__ nidsQ, const int* __restrict__ eidsQ,
           const float* __restrict__ timesQ, const int* __restrict__ curQ,
           const float* __restrict__ node_raw, const float* __restrict__ edge_raw,
           const float* __restrict__ proj_node,
           const unsigned short* __restrict__ TnL, const unsigned short* __restrict__ TnQ,
           const float* __restrict__ cstL, const float* __restrict__ cstQ,
           const unsigned* __restrict__ tpkL, const unsigned* __restrict__ tpkQ,
           const unsigned* __restrict__ wtpk,
           const float* __restrict__ bhhL, const float* __restrict__ bhhQ,
           const float* __restrict__ Wedge, const float* __restrict__ bedge,
           const float* __restrict__ Wtime, const float* __restrict__ btime,
           const float* __restrict__ Wstruct, const float* __restrict__ bstruct,
           unsigned* __restrict__ g01out, unsigned short* __restrict__ g2out)
{
    const int bq = blockIdx.x;
    const int blk = bq >> 3, qq = bq & 7;
    const int g = blk >> 9, s = blk & 511;
    const int d = threadIdx.x;

    const int*            nids  = g ? nidsQ : nidsL;
    const int*            eids  = g ? eidsQ : eidsL;
    const float*          times = g ? timesQ : timesL;
    const int*            curp  = g ? curQ : curL;
    const unsigned short* Tn    = g ? TnQ : TnL;
    const float*          cst   = g ? cstQ : cstL;
    const unsigned*       tpk   = g ? tpkQ : tpkL;
    const float*          bhh   = g ? bhhQ : bhhL;

    unsigned tp0[8], tp1[8], tp2[8], wtp[8];
#pragma unroll
    for (int q4 = 0; q4 < 2; ++q4) {
        uint4 a = *(const uint4*)(tpk + (size_t)(0 * 64 + d) * 8 + 4 * q4);
        tp0[4*q4] = a.x; tp0[4*q4+1] = a.y; tp0[4*q4+2] = a.z; tp0[4*q4+3] = a.w;
        uint4 b = *(const uint4*)(tpk + (size_t)(1 * 64 + d) * 8 + 4 * q4);
        tp1[4*q4] = b.x; tp1[4*q4+1] = b.y; tp1[4*q4+2] = b.z; tp1[4*q4+3] = b.w;
        uint4 c = *(const uint4*)(tpk + (size_t)(2 * 64 + d) * 8 + 4 * q4);
        tp2[4*q4] = c.x; tp2[4*q4+1] = c.y; tp2[4*q4+2] = c.z; tp2[4*q4+3] = c.w;
        uint4 e = *(const uint4*)(wtpk + (size_t)d * 8 + 4 * q4);
        wtp[4*q4] = e.x; wtp[4*q4+1] = e.y; wtp[4*q4+2] = e.z; wtp[4*q4+3] = e.w;
    }
    const float TE0 = cst[0*192 + d], TE1 = cst[0*192 + 64 + d], TE2 = cst[0*192 + 128 + d];
    const float TW0 = cst[1*192 + d], TW1 = cst[1*192 + 64 + d], TW2 = cst[1*192 + 128 + d];
    const float T10 = cst[2*192 + d], T11 = cst[2*192 + 64 + d], T12 = cst[2*192 + 128 + d];
    const float TB0 = cst[3*192 + d], TB1 = cst[3*192 + 64 + d], TB2 = cst[3*192 + 128 + d];
    const float CC0 = cst[4*192 + d] + bhh[d];
    const float CC1 = cst[4*192 + 64 + d] + bhh[64 + d];
    const float CC2 = cst[4*192 + 128 + d];
    const float we_l = Wedge[d];
    const float ws_l = Wstruct[d];
    const float b0_l = bedge[d] + btime[d] + 2.f * bstruct[d];
    const float tfl  = TFREQ[d & 15];

    const int cur = curp[s];
    const int csk = (int)node_raw[(size_t)cur * FF];
    const int* nrow = nids + s * LHH;
    const int* erow = eids + s * LHH;
    const float* trow = times + s * LHH;
    const int lbase = qq * 25;

    auto GATH = [&](PS& P, int i) {
        int l = lbase + i;
        int nid = nrow[l];
        int eid = erow[l];
        P.nid = nid;
        const unsigned short* tb = Tn + (size_t)nid * 192;
        P.tn0 = h16f(tb[d]);
        P.tn1 = h16f(tb[64 + d]);
        P.tn2 = h16f(tb[128 + d]);
        P.pv  = proj_node[(size_t)nid * DD + d];
        P.e0  = edge_raw[(size_t)eid * 4];
        P.sk  = node_raw[(size_t)nid * FF];
        P.t   = trow[l];
    };

    auto EMIT = [&](const PS& P, int i) {
        float cv = __cosf(P.t * tfl);
        float cx = dpp_xor1(cv);
        unsigned cp = pkrtz_u(cv, cx);
        unsigned s0 = rlu(cp, 0),  s1 = rlu(cp, 2),  s2 = rlu(cp, 4),  s3 = rlu(cp, 6);
        unsigned s4 = rlu(cp, 8),  s5 = rlu(cp, 10), s6 = rlu(cp, 12), s7 = rlu(cp, 14);
        float tf = fd2(wtp[7], s7, fd2(wtp[6], s6, fd2(wtp[5], s5, fd2(wtp[4], s4, 0.f))));
        tf = fd2(wtp[3], s3, fd2(wtp[2], s2, fd2(wtp[1], s1, fd2(wtp[0], s0, tf))));
        float flg = ((P.nid == cur) ? 1.f : 0.f) + (((int)P.sk == csk) ? 1.f : 0.f);
        float f = P.pv + P.e0 * we_l + flg * ws_l + b0_l + tf;
        float mu = f;
#pragma unroll
        for (int off = 32; off; off >>= 1) mu += __shfl_xor(mu, off);
        mu *= (1.f / 64.f);
        float dv = f - mu, var = dv * dv;
#pragma unroll
        for (int off = 32; off; off >>= 1) var += __shfl_xor(var, off);
        float rs = rsqrtf(var * (1.f / 64.f) + 1e-5f);
        float c0 = fd2(tp0[7], s7, fd2(tp0[6], s6, fd2(tp0[5], s5, fd2(tp0[4], s4, 0.f))));
        c0 = fd2(tp0[3], s3, fd2(tp0[2], s2, fd2(tp0[1], s1, fd2(tp0[0], s0, c0))));
        float c1 = fd2(tp1[7], s7, fd2(tp1[6], s6, fd2(tp1[5], s5, fd2(tp1[4], s4, 0.f))));
        c1 = fd2(tp1[3], s3, fd2(tp1[2], s2, fd2(tp1[1], s1, fd2(tp1[0], s0, c1))));
        float c2 = fd2(tp2[7], s7, fd2(tp2[6], s6, fd2(tp2[5], s5, fd2(tp2[4], s4, 0.f))));
        c2 = fd2(tp2[3], s3, fd2(tp2[2], s2, fd2(tp2[1], s1, fd2(tp2[0], s0, c2))));
        float g0 = (c0 + P.tn0 + P.e0 * TE0 + flg * TW0 + TB0 - mu * T10) * rs + CC0;
        float g1 = (c1 + P.tn1 + P.e0 * TE1 + flg * TW1 + TB1 - mu * T11) * rs + CC1;
        float g2 = (c2 + P.tn2 + P.e0 * TE2 + flg * TW2 + TB2 - mu * T12) * rs + CC2;
        size_t pos = ((size_t)blk * LHH + (lbase + i)) * 64 + d;
        g01out[pos] = packrn(g0, g1);
        g2out[pos] = f16u(g2);
    };

    // depth-2 software pipeline over 25 positions
    PS A, B, C;
    GATH(A, 0);
    GATH(B, 1);
    for (int i = 0; i < 25; ++i) {
        int inext = (i + 2 < 25) ? i + 2 : 24;
        GATH(C, inext);
        EMIT(A, i);
        A = B; B = C;
    }
}

// ---------------------------------------------------------------------------
// GRU-lite: ONE wave per sequence; only the h-recurrence.
// ---------------------------------------------------------------------------
__global__ void __launch_bounds__(64) __attribute__((amdgpu_waves_per_eu(1, 1)))
gru_lite_kernel(const unsigned* __restrict__ g01, const unsigned short* __restrict__ g2a,
                const unsigned* __restrict__ whpL, const unsigned* __restrict__ whpQ,
                const float* __restrict__ bhhL, const float* __restrict__ bhhQ,
                float* __restrict__ embL, float* __restrict__ embQ)
{
    const int blk = blockIdx.x;
    const int g = blk >> 9, s = blk & 511;
    const int d = threadIdx.x;

    const unsigned* whp = g ? whpQ : whpL;
    const float*    bhh = g ? bhhQ : bhhL;
    float*          emb = g ? embQ : embL;

    unsigned w0[32], w1[32], w2[32];
    {
        const unsigned* p0 = whp + (size_t)d * 32;
        const unsigned* p1 = whp + (size_t)(64 + d) * 32;
        const unsigned* p2 = whp + (size_t)(128 + d) * 32;
#pragma unroll
        for (int q4 = 0; q4 < 8; ++q4) {
            uint4 a = *(const uint4*)(p0 + 4 * q4);
            w0[4*q4] = a.x; w0[4*q4+1] = a.y; w0[4*q4+2] = a.z; w0[4*q4+3] = a.w;
            uint4 b = *(const uint4*)(p1 + 4 * q4);
            w1[4*q4] = b.x; w1[4*q4+1] = b.y; w1[4*q4+2] = b.z; w1[4*q4+3] = b.w;
            uint4 c = *(const uint4*)(p2 + 4 * q4);
            w2[4*q4] = c.x; w2[4*q4+1] = c.y; w2[4*q4+2] = c.z; w2[4*q4+3] = c.w;
        }
    }
#pragma unroll
    for (int i = 0; i < 32; ++i) {
        asm volatile("" : "+v"(w0[i]));
        asm volatile("" : "+v"(w1[i]));
        asm volatile("" : "+v"(w2[i]));
    }
    const float BH2 = bhh[128 + d];

    const unsigned* p01 = g01 + (size_t)blk * LHH * 64 + d;
    const unsigned short* p2 = g2a + (size_t)blk * LHH * 64 + d;

    float h = 0.f;

    auto COMPUTE = [&](unsigned pk01, unsigned pk2) {
        float g0 = f16lo(pk01), g1 = f16hi(pk01);
        float g2 = h16f((unsigned short)pk2);
        float hx = dpp_xor1(h);
        unsigned hpu = pkrtz_u(h, hx);
        float a0 = 0.f, a1 = 0.f, a2 = 0.f, e0 = 0.f, e1 = 0.f, e2 = 0.f;
#pragma unroll
        for (int q = 0; q < 32; q += 2) {
            unsigned sa = rlu(hpu, 2 * q);
            unsigned sb = rlu(hpu, 2 * q + 2);
            a0 = fd2(w0[q], sa, a0);
            a1 = fd2(w1[q], sa, a1);
            a2 = fd2(w2[q], sa, a2);
            e0 = fd2(w0[q+1], sb, e0);
            e1 = fd2(w1[q+1], sb, e1);
            e2 = fd2(w2[q+1], sb, e2);
        }
        float mv0 = a0 + e0, mv1 = a1 + e1, mv2 = a2 + e2;
        float r = sigm(g0 + mv0);
        float z = sigm(g1 + mv1);
        float n = tanh_f(g2 + r * (mv2 + BH2));
        h = (1.f - z) * n + z * h;
    };

    unsigned A01[4], A2[4], B01[4], B2[4];
#pragma unroll
    for (int i = 0; i < 4; ++i) {
        A01[i] = p01[(size_t)i * 64];
        A2[i]  = p2[(size_t)i * 64];
    }
    for (int l = 0; l < LHH; l += 8) {
#pragma unroll
        for (int i = 0; i < 4; ++i) {
            int ll = l + 4 + i;
            B01[i] = p01[(size_t)ll * 64];
            B2[i]  = p2[(size_t)ll * 64];
        }
#pragma unroll
        for (int i = 0; i < 4; ++i) COMPUTE(A01[i], A2[i]);
#pragma unroll
        for (int i = 0; i < 4; ++i) {
            int ll = l + 8 + i;
            if (ll > LHH - 1) ll = LHH - 1;
            A01[i] = p01[(size_t)ll * 64];
            A2[i]  = p2[(size_t)ll * 64];
        }
#pragma unroll
        for (int i = 0; i < 4; ++i) COMPUTE(B01[i], B2[i]);
    }
    emb[(size_t)s * DD + d] = h;
}

// ---------------------------------------------------------------------------
// K3a: dedup + CSR build. One block per batch row.
// ---------------------------------------------------------------------------
__global__ void __launch_bounds__(512)
dedup_kernel(const int* __restrict__ retrieved, const int* __restrict__ pool_nodes,
             int* __restrict__ slot_idG, float* __restrict__ disG,
             unsigned* __restrict__ startG, unsigned short* __restrict__ adjG,
             int* __restrict__ Ub)
{
    __shared__ unsigned hkey[GE_HASH];
    __shared__ int hslot[GE_HASH];
    __shared__ unsigned ekey[GE_HASH];
    __shared__ int ids[400];
    __shared__ int slot_id[400];
    __shared__ unsigned deg[400];
    __shared__ float dis[400];
    __shared__ unsigned elist[400];
    __shared__ unsigned scanA[400], scanB[400];
    __shared__ int cursor[400];
    __shared__ unsigned short adjS[800];
    __shared__ int pids[8];
    __shared__ int cntU, cntE;

    const int b = blockIdx.x;
    const int tid = threadIdx.x;

    if (tid < 8) pids[tid] = retrieved[b * 8 + tid];
    if (tid == 0) { cntU = 0; cntE = 0; }
    for (int i = tid; i < GE_HASH; i += 512) { hkey[i] = 0u; ekey[i] = 0u; }
    if (tid < 400) deg[tid] = 0u;
    __syncthreads();

    if (tid < 400) {
        int k = tid / 50, p = tid % 50;
        ids[tid] = pool_nodes[(size_t)pids[k] * 50 + p];
    }
    __syncthreads();

    if (tid < 400) {
        int idi = ids[tid];
        if (idi > 0) {
            unsigned id = (unsigned)idi;
            unsigned p = (id * 2654435761u) & (GE_HASH - 1);
            while (true) {
                unsigned old = atomicCAS(&hkey[p], 0u, id);
                if (old == 0u) {
                    int s = atomicAdd(&cntU, 1);
                    hslot[p] = s; slot_id[s] = idi;
                    break;
                }
                if (old == id) break;
                p = (p + 1) & (GE_HASH - 1);
            }
        }
    }
    __syncthreads();

    if (tid < 8 * 49) {
        int k = tid / 49, p = tid % 49;
        int u = ids[k * 50 + p], v = ids[k * 50 + p + 1];
        if (u > 0 && v > 0) {
            unsigned a = (unsigned)min(u, v), bb = (unsigned)max(u, v);
            unsigned key = a * 40000u + bb;
            unsigned p2 = (key * 2654435761u) & (GE_HASH - 1);
            while (true) {
                unsigned old = atomicCAS(&ekey[p2], 0u, key);
                if (old == 0u) {
                    int su = hlookupf(hkey, hslot, a);
                    int sv = hlookupf(hkey, hslot, bb);
                    int e = atomicAdd(&cntE, 1);
                    elist[e] = ((unsigned)su << 16) | (unsigned)sv;
                    atomicAdd(&deg[su], 1u);
                    atomicAdd(&deg[sv], 1u);
                    break;
                }
                if (old == key) break;
                p2 = (p2 + 1) & (GE_HASH - 1);
            }
        }
    }
    __syncthreads();

    const int U = cntU, EC = cntE;
    if (tid < 400) {
        dis[tid] = rsqrtf((float)deg[tid] + 1.0f);
        scanA[tid] = deg[tid];
    }
    __syncthreads();

    unsigned* src = scanA;
    unsigned* dst = scanB;
    for (int off = 1; off < 400; off <<= 1) {
        if (tid < 400)
            dst[tid] = src[tid] + ((tid >= off) ? src[tid - off] : 0u);
        __syncthreads();
        unsigned* t = src; src = dst; dst = t;
    }
    if (tid < 400) {
        unsigned st = src[tid] - deg[tid];
        cursor[tid] = (int)st;
        if (tid < U) startG[(size_t)b * 404 + tid] = st;
    }
    if (tid == 0) {
        startG[(size_t)b * 404 + U] = (U > 0) ? src[U - 1] : 0u;
        Ub[b] = U;
    }
    __syncthreads();

    if (tid < EC) {
        unsigned pk = elist[tid];
        int su = (int)(pk >> 16), sv = (int)(pk & 0xffffu);
        int pu = atomicAdd(&cursor[su], 1);
        adjS[pu] = (unsigned short)sv;
        int pv = atomicAdd(&cursor[sv], 1);
        adjS[pv] = (unsigned short)su;
    }
    __syncthreads();

    if (tid < 400) {
        slot_idG[(size_t)b * 400 + tid] = (tid < U) ? slot_id[tid] : 0;
        disG[(size_t)b * 400 + tid] = dis[tid];
    }
    for (int i = tid; i < 800; i += 512) {
        unsigned tot = (U > 0) ? src[U - 1] : 0u;
        adjG[(size_t)b * 800 + i] = (i < (int)tot) ? adjS[i] : (unsigned short)0;
    }
}

// ---------------------------------------------------------------------------
// K3b: slot-parallel GCN aggregate + relu + partial sum. grid (BB, 4).
// ---------------------------------------------------------------------------
__global__ void __launch_bounds__(256)
gcn_agg_kernel(const float* __restrict__ hgcn, const float* __restrict__ gcn_b,
               const int* __restrict__ slot_idG, const float* __restrict__ disG,
               const unsigned* __restrict__ startG, const unsigned short* __restrict__ adjG,
               const int* __restrict__ Ub, float* __restrict__ part)
{
    __shared__ int sidS[400];
    __shared__ float disS[400];
    __shared__ unsigned stS[404];
    __shared__ unsigned short adjS[800];
    __shared__ float red[4][64];

    const int b = blockIdx.x, q = blockIdx.y;
    const int tid = threadIdx.x;
    const int lane = tid & 63, w = tid >> 6;
    const int U = Ub[b];

    for (int i = tid; i < 400; i += 256) {
        sidS[i] = slot_idG[(size_t)b * 400 + i];
        disS[i] = disG[(size_t)b * 400 + i];
    }
    for (int i = tid; i < 404; i += 256) stS[i] = startG[(size_t)b * 404 + i];
    for (int i = tid; i < 800; i += 256) adjS[i] = adjG[(size_t)b * 800 + i];
    __syncthreads();

    const float gb = gcn_b[lane];
    float acc = 0.f;

    for (int s = q * 4 + w; s < U; s += 16) {
        int nid = sidS[s];
        float ds = disS[s];
        float v = fmaf(ds * ds, hgcn[(size_t)nid * 64 + lane], gb);
        int a0 = (int)stS[s];
        int cnt = (int)stS[s + 1] - a0;
        for (int e0 = 0; e0 < cnt; e0 += 4) {
            float hv[4], nr[4];
#pragma unroll
            for (int j = 0; j < 4; ++j) {
                int e = e0 + j;
                int ec = (e < cnt) ? e : cnt - 1;
                int o = adjS[a0 + ec];
                nr[j] = (e < cnt) ? ds * disS[o] : 0.f;
                hv[j] = hgcn[(size_t)sidS[o] * 64 + lane];
            }
            v += nr[0] * hv[0] + nr[1] * hv[1] + nr[2] * hv[2] + nr[3] * hv[3];
        }
        acc += fmaxf(v, 0.f);
    }

    red[w][lane] = acc;
    __syncthreads();
    if (tid < 64)
        part[((size_t)b * 4 + q) * 64 + tid] =
            red[0][tid] + red[1][tid] + red[2][tid] + red[3][tid];
}

// ---------------------------------------------------------------------------
// K4: fusion + output heads (consumes GCN partials).
// ---------------------------------------------------------------------------
__global__ void __launch_bounds__(64)
head_kernel(const float* __restrict__ local_emb, const float* __restrict__ part,
            const int* __restrict__ Ub, const float* __restrict__ q_emb,
            const float* __restrict__ fus_W, const float* __restrict__ fus_b,
            const float* __restrict__ out_W, const float* __restrict__ out_b,
            float* __restrict__ out)
{
    __shared__ float cat[128];
    __shared__ float fus[64];
    __shared__ float qv[64];
    const int b = blockIdx.x, d = threadIdx.x;
    cat[d] = local_emb[(size_t)b * 64 + d];
    {
        const float* pb = part + (size_t)b * 4 * 64;
        float gsum = pb[d] + pb[64 + d] + pb[128 + d] + pb[192 + d];
        cat[64 + d] = gsum / (float)max(Ub[b], 1);
    }
    qv[d] = q_emb[(size_t)b * 64 + d];
    __syncthreads();
    float acc = fus_b[d];
    const float* fw = fus_W + (size_t)d * 128;
#pragma unroll 4
    for (int k = 0; k < 128; ++k) acc += cat[k] * fw[k];
    fus[d] = fmaxf(acc, 0.f);
    __syncthreads();
    float o0 = out_b[d], o1 = out_b[d];
    const float* ow = out_W + (size_t)d * 64;
#pragma unroll 4
    for (int k = 0; k < 64; ++k) { float ww = ow[k]; o0 += fus[k] * ww; o1 += qv[k] * ww; }
    out[(size_t)b * 64 + d] = o0;
    out[(size_t)BB * 64 + (size_t)b * 64 + d] = o1;
}

// ---------------------------------------------------------------------------
extern "C" void kernel_launch(void* const* d_in, const int* in_sizes, int n_in,
                              void* d_out, int out_size, void* d_ws, size_t ws_size,
                              hipStream_t stream)
{
    const int*   src_ids    = (const int*)d_in[0];
    const int*   dst_ids    = (const int*)d_in[1];
    const int*   l_nids     = (const int*)d_in[2];
    const int*   l_eids     = (const int*)d_in[3];
    const float* l_times    = (const float*)d_in[4];
    const int*   d_nids     = (const int*)d_in[5];
    const int*   d_eids     = (const int*)d_in[6];
    const float* d_times    = (const float*)d_in[7];
    const int*   retr       = (const int*)d_in[8];
    const float* node_raw   = (const float*)d_in[9];
    const float* edge_raw   = (const float*)d_in[10];
    const int*   pool_nodes = (const int*)d_in[11];
    const float* Wfeat  = (const float*)d_in[12];
    const float* bfeat  = (const float*)d_in[13];
    const float* Wedge  = (const float*)d_in[14];
    const float* bedge  = (const float*)d_in[15];
    const float* Wtime  = (const float*)d_in[16];
    const float* btime  = (const float*)d_in[17];
    const float* Wstruct= (const float*)d_in[18];
    const float* bstruct= (const float*)d_in[19];
    const float* ln_g   = (const float*)d_in[20];
    const float* ln_b   = (const float*)d_in[21];
    const float* gruL_Wih = (const float*)d_in[22];
    const float* gruL_Whh = (const float*)d_in[23];
    const float* gruL_bih = (const float*)d_in[24];
    const float* gruL_bhh = (const float*)d_in[25];
    const float* gruQ_Wih = (const float*)d_in[26];
    const float* gruQ_Whh = (const float*)d_in[27];
    const float* gruQ_bih = (const float*)d_in[28];
    const float* gruQ_bhh = (const float*)d_in[29];
    const float* gcn_W  = (const float*)d_in[30];
    const float* gcn_b  = (const float*)d_in[31];
    const float* fus_W  = (const float*)d_in[32];
    const float* fus_b  = (const float*)d_in[33];
    const float* out_W  = (const float*)d_in[34];
    const float* out_b  = (const float*)d_in[35];

    char* wsb = (char*)d_ws;
    auto alloc = [&](size_t bytes) -> void* {
        void* p = (void*)wsb;
        wsb += (bytes + 255) & ~(size_t)255;
        return p;
    };
    float*          proj_node = (float*)alloc((size_t)NN * DD * 4);
    float*          hgcn      = (float*)alloc((size_t)NN * DD * 4);
    unsigned short* TnL16     = (unsigned short*)alloc((size_t)NN * 192 * 2);
    unsigned short* TnQ16     = (unsigned short*)alloc((size_t)NN * 192 * 2);
    float*          cstL      = (float*)alloc(4096 * 4);
    float*          cstQ      = (float*)alloc(4096 * 4);
    unsigned*       whpL      = (unsigned*)alloc(192 * 32 * 4);
    unsigned*       whpQ      = (unsigned*)alloc(192 * 32 * 4);
    unsigned*       tpkL      = (unsigned*)alloc(192 * 8 * 4);
    unsigned*       tpkQ      = (unsigned*)alloc(192 * 8 * 4);
    unsigned*       wtpk      = (unsigned*)alloc(64 * 8 * 4);
    unsigned*       g01       = (unsigned*)alloc((size_t)2 * BB * LHH * 64 * 4);
    unsigned short* g2a       = (unsigned short*)alloc((size_t)2 * BB * LHH * 64 * 2);
    int*            slot_idG  = (int*)alloc((size_t)BB * 400 * 4);
    float*          disG      = (float*)alloc((size_t)BB * 400 * 4);
    unsigned*       startG    = (unsigned*)alloc((size_t)BB * 404 * 4);
    unsigned short* adjG      = (unsigned short*)alloc((size_t)BB * 800 * 2);
    int*            Ubuf      = (int*)alloc((size_t)BB * 4);
    float*          part      = (float*)alloc((size_t)BB * 4 * 64 * 4);
    float*          local_emb = (float*)alloc((size_t)BB * DD * 4);
    float*          q_emb     = (float*)alloc((size_t)BB * DD * 4);

    dim3 g1((NN + 127) / 128);
    gemm_nt_kernel<FF><<<g1, 256, 0, stream>>>(node_raw, Wfeat, bfeat, proj_node, NN);

    consts_kernel<<<2, 192, 0, stream>>>(gruL_Wih, gruL_bih, gruL_Whh, cstL, whpL, tpkL,
                                         gruQ_Wih, gruQ_bih, gruQ_Whh, cstQ, whpQ, tpkQ,
                                         wtpk, ln_g, ln_b, Wedge, bedge, Wtime, btime,
                                         Wstruct, bstruct);

    tn_gemm_kernel<<<dim3(NN / 64, 2), 256, 0, stream>>>(proj_node, gruL_Wih, gruQ_Wih,
                                                         ln_g, TnL16, TnQ16);

    dedup_kernel<<<BB, 512, 0, stream>>>(retr, pool_nodes, slot_idG, disG,
                                         startG, adjG, Ubuf);

    pre_kernel<<<2 * BB * 8, 64, 0, stream>>>(
        l_nids, l_eids, l_times, dst_ids,
        d_nids, d_eids, d_times, src_ids,
        node_raw, edge_raw, proj_node, TnL16, TnQ16, cstL, cstQ,
        tpkL, tpkQ, wtpk, gruL_bhh, gruQ_bhh,
        Wedge, bedge, Wtime, btime, Wstruct, bstruct,
        g01, g2a);

    gemm_nt_kernel<DD><<<g1, 256, 0, stream>>>(proj_node, gcn_W, nullptr, hgcn, NN);

    gru_lite_kernel<<<2 * BB, 64, 0, stream>>>(
        g01, g2a, whpL, whpQ, gruL_bhh, gruQ_bhh, local_emb, q_emb);

    gcn_agg_kernel<<<dim3(BB, 4), 256, 0, stream>>>(
        hgcn, gcn_b, slot_idG, disG, startG, adjG, Ubuf, part);

    head_kernel<<<BB, 64, 0, stream>>>(local_emb, part, Ubuf, q_emb,
        fus_W, fus_b, out_W, out_b, (float*)d_out);
}